// Round 10
// baseline (1535.190 us; speedup 1.0000x reference)
//
#include <hip/hip_runtime.h>
#include <math.h>

#define SEQ     2048
#define NB      2
#define NHEADS  32
#define DHEAD   128
#define HID     4096
#define NQKV    12288
#define T_TOKENS (NB*SEQ)

typedef _Float16 half8 __attribute__((ext_vector_type(8)));
typedef float v4f __attribute__((ext_vector_type(4)));

__device__ __forceinline__ void gload_lds16(const void* g, void* l) {
    __builtin_amdgcn_global_load_lds(
        (__attribute__((address_space(1))) void*)(void*)(g),
        (__attribute__((address_space(3))) void*)(unsigned)(unsigned long long)(l),
        16, 0, 0);
}

__device__ __forceinline__ v4f mfma16(half8 a, half8 b, v4f c) {
    return __builtin_amdgcn_mfma_f32_16x16x32_f16(a, b, c, 0, 0, 0);
}

// ---------------- routing ----------------
__global__ void route_kernel(const int* __restrict__ tt, int* counts, int* idx) {
    int t = blockIdx.x * blockDim.x + threadIdx.x;
    if (t >= T_TOKENS) return;
    int s = t & (SEQ - 1);
    bool vm = (s < SEQ - 1) && (tt[t] == 1) && (tt[t + 1] == 1);
    int e = vm ? 0 : 1;
    int p = atomicAdd(&counts[e], 1);
    idx[e * T_TOKENS + p] = t;
}

// ---------------- RoPE cos/sin table (accurate, once per call) ----------------
__global__ void rope_table_kernel(const int* __restrict__ pos_ids, float2* __restrict__ tab) {
    int i = blockIdx.x * blockDim.x + threadIdx.x;
    if (i >= T_TOKENS * 64) return;
    int tok = i >> 6, j = i & 63;
    float invf = (float)pow(10000.0, -(double)j * (1.0 / 64.0));
    float ang = (float)pos_ids[tok] * invf;
    double ds, dc;
    sincos((double)ang, &ds, &dc);
    tab[i] = make_float2((float)dc, (float)ds);
}

// ---------------- fp32 -> fp16 ----------------
__global__ void cvt_f32_f16(const float* __restrict__ src, _Float16* __restrict__ dst, int n4) {
    int i = blockIdx.x * blockDim.x + threadIdx.x;
    if (i >= n4) return;
    float4 v = ((const float4*)src)[i];
    union { _Float16 h[4]; uint2 u; } p;
    p.h[0] = (_Float16)v.x; p.h[1] = (_Float16)v.y;
    p.h[2] = (_Float16)v.z; p.h[3] = (_Float16)v.w;
    ((uint2*)dst)[i] = p.u;
}

// ---------------- W [K][N] f32 -> WT [N][K] f16 ----------------
__global__ void transpose_cvt(const float* __restrict__ W, _Float16* __restrict__ WT,
                              int K, int N) {
    __shared__ _Float16 t[64][72];
    const int n0 = blockIdx.x * 64, k0 = blockIdx.y * 64;
    const int cr = threadIdx.x & 15, rr = threadIdx.x >> 4;
#pragma unroll
    for (int it = 0; it < 4; ++it) {
        int r = rr + it * 16;
        float4 v = *(const float4*)&W[(size_t)(k0 + r) * N + n0 + cr * 4];
        t[cr*4+0][r] = (_Float16)v.x; t[cr*4+1][r] = (_Float16)v.y;
        t[cr*4+2][r] = (_Float16)v.z; t[cr*4+3][r] = (_Float16)v.w;
    }
    __syncthreads();
#pragma unroll
    for (int it = 0; it < 4; ++it) {
        int r = rr + it * 16;
        union { _Float16 h[4]; uint2 u; } p;
#pragma unroll
        for (int j = 0; j < 4; ++j) p.h[j] = t[r][cr*4+j];
        *(uint2*)&WT[(size_t)(n0 + r) * K + k0 + cr * 4] = p.u;
    }
}

// ---------------- V [b,s,h,d] -> VT [bh][d][s] ----------------
__global__ void transpose_v(const _Float16* __restrict__ vin, _Float16* __restrict__ vout) {
    __shared__ _Float16 t[64][72];
    const int s0 = blockIdx.x * 64;
    const int d0 = blockIdx.y * 64;
    const int bh = blockIdx.z;
    const int b = bh >> 5, h = bh & 31;
    const int cr = threadIdx.x & 15, rr = threadIdx.x >> 4;
#pragma unroll
    for (int it = 0; it < 4; ++it) {
        int sl = rr + it * 16;
        union { _Float16 h4[4]; uint2 u; } p;
        p.u = *(const uint2*)&vin[(size_t)(b * SEQ + s0 + sl) * HID + h * DHEAD + d0 + cr * 4];
#pragma unroll
        for (int j = 0; j < 4; ++j) t[cr*4+j][sl] = p.h4[j];
    }
    __syncthreads();
#pragma unroll
    for (int it = 0; it < 4; ++it) {
        int dl = rr + it * 16;
        union { _Float16 h4[4]; uint2 u; } p;
#pragma unroll
        for (int j = 0; j < 4; ++j) p.h4[j] = t[dl][cr*4+j];
        *(uint2*)&vout[((size_t)bh * DHEAD + d0 + dl) * SEQ + s0 + cr * 4] = p.u;
    }
}

// ---------------- gathered-row expert GEMM ----------------
// MODE 0: qkv + fused RoPE scatter.  MODE 1: dense -> fp32 out.
// A [T][4096] f16, BT [N][4096] f16. Tile 128x128, BK=32.
// v6 = round-6 pipeline + round-7 wave split (deconfounded):
//  - depth-3 counted-vmcnt pipeline (T4), 4 LDS buffers, vmcnt(8), never 0
//    in the main loop (round-5/6 proven: -46 us).
//  - 2x2 wave split: wave (wm,wn) computes rows wm*64..+64, cols interleaved
//    (wn+2j)*16 (RoPE pair d/d+64 in-wave). LDS reads 10 -> 8 per 16 MFMA
//    (-20% on the binding LDS-BW resource).
//  - intra-row chunk swizzle (both-sides) -> bank conflicts measured 0.
// Bit-exact vs round-0 (K-order and math unchanged).
template <int MODE, int NCT>
__global__ __launch_bounds__(256, 2)
void gemm_expert(const _Float16* __restrict__ A,
                 const _Float16* __restrict__ BT0,
                 const _Float16* __restrict__ BT1,
                 const int* __restrict__ counts,
                 const int* __restrict__ idx_all,
                 const float2* __restrict__ rope,
                 _Float16* __restrict__ qbuf,
                 _Float16* __restrict__ kbuf,
                 _Float16* __restrict__ vbuf,
                 float* __restrict__ out) {
    const int e = blockIdx.z;
    const int count = counts[e];

    // ---- locality remap (bijective): f -> (ct, rt) ----
    const int f   = blockIdx.x + NCT * blockIdx.y;  // dispatch-order flat id
    const int xcd = f & 7;                          // HW round-robins XCDs
    const int g   = f >> 3;                         // per-XCD sequence
    const int c   = g >> 6;                         // ct-chunk (2 cts per chunk)
    const int wi  = g & 63;
    const int rt  = wi >> 1;
    const int ct  = xcd * (NCT / 8) + c * 2 + (wi & 1);

    if (rt * 128 >= count) return;
    const int* idx = idx_all + e * T_TOKENS;
    const _Float16* BT = e ? BT1 : BT0;

    __shared__ _Float16 sA[4][128 * 32];
    __shared__ _Float16 sB[4][128 * 32];

    const int tid = threadIdx.x;
    const int w = tid >> 6, lane = tid & 63;
    const int col = lane & 15, quad = lane >> 4;
    const int wm = w >> 1, wn = w & 1;

    const int r0 = (w * 2 + 0) * 16 + (lane >> 2);
    const int r1 = (w * 2 + 1) * 16 + (lane >> 2);
    int g0 = rt * 128 + r0; if (g0 > count - 1) g0 = count - 1;
    int g1 = rt * 128 + r1; if (g1 > count - 1) g1 = count - 1;
    const int tok0 = idx[g0], tok1 = idx[g1];
    // staging row within tile has row&15 == lane>>2; swizzle key (row>>1)&3
    // == (lane>>3)&3. Source chunk pre-swizzled; LDS dest linear.
    const int schk = (lane & 3) ^ ((lane >> 3) & 3);
    const _Float16* ag0 = A + (size_t)tok0 * HID + schk * 8;
    const _Float16* ag1 = A + (size_t)tok1 * HID + schk * 8;
    const _Float16* bg0 = BT + (size_t)(ct * 128 + r0) * HID + schk * 8;
    const _Float16* bg1 = BT + (size_t)(ct * 128 + r1) * HID + schk * 8;
    const int sa_off0 = (w * 2 + 0) * 512;
    const int sa_off1 = (w * 2 + 1) * 512;

    v4f acc[4][4];
#pragma unroll
    for (int i = 0; i < 4; ++i)
#pragma unroll
        for (int j = 0; j < 4; ++j) { v4f z = {0.f, 0.f, 0.f, 0.f}; acc[i][j] = z; }

    // fragment-read rows are (mult of 16)+col -> swizzle key (col>>1)&3
    const int kofq = (quad ^ ((col >> 1) & 3)) * 8;

    auto stage = [&](int buf) {
        gload_lds16(ag0, &sA[buf][sa_off0]); gload_lds16(ag1, &sA[buf][sa_off1]);
        gload_lds16(bg0, &sB[buf][sa_off0]); gload_lds16(bg1, &sB[buf][sa_off1]);
        ag0 += 32; ag1 += 32; bg0 += 32; bg1 += 32;
    };
    auto compute = [&](int cur) {
        half8 a[4], b[4];
#pragma unroll
        for (int i = 0; i < 4; ++i)
            a[i] = *(const half8*)&sA[cur][(wm * 64 + i * 16 + col) * 32 + kofq];
#pragma unroll
        for (int j = 0; j < 4; ++j)
            b[j] = *(const half8*)&sB[cur][((wn + 2 * j) * 16 + col) * 32 + kofq];
#pragma unroll
        for (int i = 0; i < 4; ++i)
#pragma unroll
            for (int j = 0; j < 4; ++j)
                acc[i][j] = mfma16(a[i], b[j], acc[i][j]);
    };

    const int NK = HID / 32;   // 128
    // prologue: 3 stages in flight
    stage(0); stage(1); stage(2);

    for (int kt = 0; kt < NK - 3; ++kt) {
        asm volatile("s_waitcnt vmcnt(8)" ::: "memory");  // stage(kt) retired
        __builtin_amdgcn_s_barrier();                     // cross-wave publish
        asm volatile("" ::: "memory");
        stage((kt + 3) & 3);                              // 12 loads in flight again
        compute(kt & 3);
    }
    // tail: kt = NK-3, NK-2, NK-1 (no more stages; counts drain 8 -> 4 -> 0)
    asm volatile("s_waitcnt vmcnt(8)" ::: "memory");
    __builtin_amdgcn_s_barrier();
    asm volatile("" ::: "memory");
    compute((NK - 3) & 3);
    asm volatile("s_waitcnt vmcnt(4)" ::: "memory");
    __builtin_amdgcn_s_barrier();
    asm volatile("" ::: "memory");
    compute((NK - 2) & 3);
    asm volatile("s_waitcnt vmcnt(0)" ::: "memory");
    __builtin_amdgcn_s_barrier();
    asm volatile("" ::: "memory");
    compute((NK - 1) & 3);

    const int n0 = ct * 128;
    if (MODE == 1) {
#pragma unroll
        for (int i = 0; i < 4; ++i)
#pragma unroll
            for (int r = 0; r < 4; ++r) {
                int rg = rt * 128 + wm * 64 + i * 16 + quad * 4 + r;
                if (rg >= count) continue;
                int tok = idx[rg];
                float* dst = out + (size_t)tok * HID + n0;
#pragma unroll
                for (int j = 0; j < 4; ++j) dst[(wn + 2 * j) * 16 + col] = acc[i][j][r];
            }
    } else {
        const int sec = n0 >> 12;          // 0=q 1=k 2=v
        const int h = (n0 >> 7) & 31;
#pragma unroll
        for (int i = 0; i < 4; ++i)
#pragma unroll
            for (int r = 0; r < 4; ++r) {
                int rg = rt * 128 + wm * 64 + i * 16 + quad * 4 + r;
                if (rg >= count) continue;
                int tok = idx[rg];
                int b = tok >> 11, s = tok & (SEQ - 1);
                if (sec == 2) {
                    _Float16* dst = vbuf + (size_t)tok * HID + h * DHEAD;
#pragma unroll
                    for (int j = 0; j < 4; ++j) dst[(wn + 2 * j) * 16 + col] = (_Float16)acc[i][j][r];
                } else {
                    _Float16* dst = (sec ? kbuf : qbuf) + ((size_t)(b * NHEADS + h) * SEQ + s) * DHEAD;
                    const float2* tp = rope + (size_t)tok * 64;
#pragma unroll
                    for (int j = 0; j < 2; ++j) {
                        int d = (wn + 2 * j) * 16 + col;
                        float2 cs = tp[d];
                        float x = acc[i][j][r], y = acc[i][j + 2][r];
                        dst[d]      = (_Float16)(x * cs.x - y * cs.y);
                        dst[d + 64] = (_Float16)(y * cs.x + x * cs.y);
                    }
                }
            }
    }
}

// ---------------- flash attention (round-9 version, unchanged) ----------------
// KVBLK=64, double-buffered K/V, dedicated P region (own-wave rows -> no P
// barriers), ONE barrier per kv-tile at iteration end. Next tile's
// global_load_lds issued BEFORE compute so HBM/L2 latency hides under
// QK+softmax+PV (T3-minimum). LDS 80KB -> 2 blocks/CU. setprio around MFMA.
__global__ __launch_bounds__(256, 2)
void attn_kernel(const _Float16* __restrict__ qbuf,
                 const _Float16* __restrict__ kbuf,
                 const _Float16* __restrict__ vt,
                 _Float16* __restrict__ ctx) {
    // XCD-aware decode of flat block id: all 16 q-tiles of a head on one XCD,
    // qt paired u/15-u across co-resident rounds for load balance.
    const int f   = blockIdx.x;            // 0..1023
    const int xcd = f & 7;
    const int t   = f >> 3;
    const int s   = t & 31;
    const int rr  = t >> 5;
    const int u   = s & 15, g = s >> 4;
    const int bh  = xcd * 8 + rr * 2 + g;
    const int qt  = (rr & 1) ? (15 - u) : u;

    const int b = bh >> 5, h = bh & 31;
    const int tid = threadIdx.x;
    const int w = tid >> 6, lane = tid & 63;
    const int col = lane & 15, quad = lane >> 4;

    __shared__ _Float16 sK[2][64 * 128];   // K [64][128], swizzled, double-buffered
    __shared__ _Float16 sV[2][128 * 64];   // V [d=128][s=64], swizzled, double-buffered
    __shared__ _Float16 sP[128 * 64];      // P [128][64], swizzled, per-wave rows

    half8 qf[2][4];
    const _Float16 qscale = (_Float16)0.08838834764831845f;  // 1/sqrt(128)
#pragma unroll
    for (int mt = 0; mt < 2; ++mt)
#pragma unroll
        for (int kc = 0; kc < 4; ++kc) {
            int row = qt * 128 + w * 32 + mt * 16 + col;
            half8 v = *(const half8*)&qbuf[((size_t)bh * SEQ + row) * DHEAD + kc * 32 + quad * 8];
            qf[mt][kc] = v * qscale;
        }

    float mrow[2][4], lrow[2][4];
    v4f o[2][8];
#pragma unroll
    for (int mt = 0; mt < 2; ++mt)
#pragma unroll
        for (int r = 0; r < 4; ++r) { mrow[mt][r] = -3.0e38f; lrow[mt][r] = 0.f; }
#pragma unroll
    for (int i = 0; i < 2; ++i)
#pragma unroll
        for (int j = 0; j < 8; ++j) { v4f z = {0.f, 0.f, 0.f, 0.f}; o[i][j] = z; }

    const int cxor = col & 7;
    const int vs_chk = (lane & 7) ^ (lane >> 3);
    const int nkt = 2 * qt + 2;

    const _Float16* kg0 = kbuf + (size_t)bh * SEQ * DHEAD;
    const _Float16* vg0 = vt + (size_t)bh * DHEAD * SEQ;

    auto stage = [&](int kt, int buf) {
        const _Float16* kg = kg0 + (size_t)kt * 64 * DHEAD;
        const _Float16* vg = vg0 + kt * 64;
#pragma unroll
        for (int op = 0; op < 4; ++op) {
            int r0 = (w * 4 + op) * 4;            // K: 4 rows x 16 chunks per op
            int krow = r0 + quad;
            int kcs = col ^ (krow & 7);
            gload_lds16(kg + (size_t)krow * DHEAD + kcs * 8, &sK[buf][r0 * 128]);
            int d0 = (w * 4 + op) * 8;            // V: 8 rows x 8 chunks per op
            int vrow = d0 + (lane >> 3);
            gload_lds16(vg + (size_t)vrow * SEQ + vs_chk * 8, &sV[buf][d0 * 64]);
        }
    };

    stage(0, 0);
    __syncthreads();   // drain prologue stage

    for (int kt = 0; kt < nkt; ++kt) {
        const int cur = kt & 1;
        // issue next tile's loads first -- they complete during compute below
        if (kt + 1 < nkt) stage(kt + 1, cur ^ 1);

        v4f sc[2][4];
#pragma unroll
        for (int i = 0; i < 2; ++i)
#pragma unroll
            for (int j = 0; j < 4; ++j) { v4f z = {0.f, 0.f, 0.f, 0.f}; sc[i][j] = z; }
        __builtin_amdgcn_s_setprio(1);
#pragma unroll
        for (int kc = 0; kc < 4; ++kc) {
            const int kof = ((kc * 4 + quad) ^ cxor) * 8;
#pragma unroll
            for (int nt = 0; nt < 4; ++nt) {
                half8 bf = *(const half8*)&sK[cur][(size_t)(nt * 16 + col) * 128 + kof];
                sc[0][nt] = mfma16(qf[0][kc], bf, sc[0][nt]);
                sc[1][nt] = mfma16(qf[1][kc], bf, sc[1][nt]);
            }
        }
        __builtin_amdgcn_s_setprio(0);

        if (kt >= 2 * qt) {   // only the last two tiles touch the diagonal
#pragma unroll
            for (int mt = 0; mt < 2; ++mt)
#pragma unroll
                for (int nt = 0; nt < 4; ++nt)
#pragma unroll
                    for (int r = 0; r < 4; ++r) {
                        int rowa = qt * 128 + w * 32 + mt * 16 + quad * 4 + r;
                        int cola = kt * 64 + nt * 16 + col;
                        if (cola > rowa) sc[mt][nt][r] = -3.0e38f;
                    }
        }

#pragma unroll
        for (int mt = 0; mt < 2; ++mt)
#pragma unroll
            for (int r = 0; r < 4; ++r) {
                float mx = sc[mt][0][r];
#pragma unroll
                for (int nt = 1; nt < 4; ++nt) mx = fmaxf(mx, sc[mt][nt][r]);
                mx = fmaxf(mx, __shfl_xor(mx, 1));
                mx = fmaxf(mx, __shfl_xor(mx, 2));
                mx = fmaxf(mx, __shfl_xor(mx, 4));
                mx = fmaxf(mx, __shfl_xor(mx, 8));
                float newm = fmaxf(mrow[mt][r], mx);
                float alpha = __expf(mrow[mt][r] - newm);
                mrow[mt][r] = newm;
                float rs = 0.f;
#pragma unroll
                for (int nt = 0; nt < 4; ++nt) {
                    float p = __expf(sc[mt][nt][r] - newm);
                    sc[mt][nt][r] = p;
                    rs += p;
                }
                rs += __shfl_xor(rs, 1); rs += __shfl_xor(rs, 2);
                rs += __shfl_xor(rs, 4); rs += __shfl_xor(rs, 8);
                lrow[mt][r] = lrow[mt][r] * alpha + rs;
#pragma unroll
                for (int nt = 0; nt < 8; ++nt) o[mt][nt][r] *= alpha;
            }

        // P -> sP (each wave owns rows w*32..w*32+31: no cross-wave barrier)
#pragma unroll
        for (int mt = 0; mt < 2; ++mt)
#pragma unroll
            for (int nt = 0; nt < 4; ++nt)
#pragma unroll
                for (int r = 0; r < 4; ++r) {
                    int rp = w * 32 + mt * 16 + quad * 4 + r;
                    int colh = nt * 16 + col;
                    int c = (colh >> 3) ^ (rp & 7);
                    sP[(size_t)rp * 64 + c * 8 + (colh & 7)] = (_Float16)sc[mt][nt][r];
                }

        __builtin_amdgcn_s_setprio(1);
#pragma unroll
        for (int kc = 0; kc < 2; ++kc) {
            const int kof = ((kc * 4 + quad) ^ cxor) * 8;
            half8 p0 = *(const half8*)&sP[(size_t)(w * 32 + col) * 64 + kof];
            half8 p1 = *(const half8*)&sP[(size_t)(w * 32 + 16 + col) * 64 + kof];
#pragma unroll
            for (int nt = 0; nt < 8; ++nt) {
                half8 vf = *(const half8*)&sV[cur][(size_t)(nt * 16 + col) * 64 + kof];
                o[0][nt] = mfma16(p0, vf, o[0][nt]);
                o[1][nt] = mfma16(p1, vf, o[1][nt]);
            }
        }
        __builtin_amdgcn_s_setprio(0);

        // single barrier: drains next-tile stage (vmcnt) + guards K/V reuse
        __syncthreads();
    }

#pragma unroll
    for (int mt = 0; mt < 2; ++mt)
#pragma unroll
        for (int r = 0; r < 4; ++r) {
            int rowa = qt * 128 + w * 32 + mt * 16 + quad * 4 + r;
            float inv = 1.0f / lrow[mt][r];
            _Float16* dst = ctx + ((size_t)b * SEQ + rowa) * HID + h * DHEAD;
#pragma unroll
            for (int nt = 0; nt < 8; ++nt)
                dst[nt * 16 + col] = (_Float16)(o[mt][nt][r] * inv);
        }
}

extern "C" void kernel_launch(void* const* d_in, const int* in_sizes, int n_in,
                              void* d_out, int out_size, void* d_ws, size_t ws_size,
                              hipStream_t stream) {
    const float* hidden = (const float*)d_in[0];
    const int*   tt     = (const int*)d_in[1];
    const int*   pos    = (const int*)d_in[2];
    const float* wvq    = (const float*)d_in[3];
    const float* wlq    = (const float*)d_in[4];
    const float* wvd    = (const float*)d_in[5];
    const float* wld    = (const float*)d_in[6];
    float* out = (float*)d_out;

    char* ws = (char*)d_ws;
    size_t off = 0;
    auto alloc = [&](size_t bytes) {
        char* p = ws + off;
        off += (bytes + 255) & ~(size_t)255;
        return p;
    };
    const size_t TOKB = (size_t)T_TOKENS * HID * sizeof(_Float16);  // 33.5 MB
    _Float16* h16  = (_Float16*)alloc(TOKB);                        // later reused as vT
    _Float16* wvqT = (_Float16*)alloc((size_t)NQKV * HID * 2);
    _Float16* wlqT = (_Float16*)alloc((size_t)NQKV * HID * 2);
    _Float16* wvdT = (_Float16*)alloc((size_t)HID * HID * 2);
    _Float16* wldT = (_Float16*)alloc((size_t)HID * HID * 2);
    _Float16* qb   = (_Float16*)alloc(TOKB);
    _Float16* kb   = (_Float16*)alloc(TOKB);
    _Float16* vtmp = (_Float16*)alloc(TOKB);                        // later reused as ctx
    int* counts = (int*)alloc(2 * sizeof(int));
    int* idx    = (int*)alloc(2 * T_TOKENS * sizeof(int));
    float2* rope = (float2*)alloc((size_t)T_TOKENS * 64 * sizeof(float2));
    _Float16* vT  = h16;    // hidden16 dead after QKV GEMM
    _Float16* ctx = vtmp;   // v token-major dead after transpose_v

    hipMemsetAsync(counts, 0, 2 * sizeof(int), stream);
    route_kernel<<<T_TOKENS / 256, 256, 0, stream>>>(tt, counts, idx);
    rope_table_kernel<<<(T_TOKENS * 64) / 256, 256, 0, stream>>>(pos, rope);
    cvt_f32_f16<<<(T_TOKENS * HID / 4) / 256, 256, 0, stream>>>(hidden, h16, T_TOKENS * HID / 4);
    transpose_cvt<<<dim3(NQKV / 64, HID / 64), 256, 0, stream>>>(wvq, wvqT, HID, NQKV);
    transpose_cvt<<<dim3(NQKV / 64, HID / 64), 256, 0, stream>>>(wlq, wlqT, HID, NQKV);
    transpose_cvt<<<dim3(HID / 64, HID / 64), 256, 0, stream>>>(wvd, wvdT, HID, HID);
    transpose_cvt<<<dim3(HID / 64, HID / 64), 256, 0, stream>>>(wld, wldT, HID, HID);
    gemm_expert<0, NQKV / 128><<<dim3(NQKV / 128, T_TOKENS / 128, 2), 256, 0, stream>>>(
        h16, wvqT, wlqT, counts, idx, rope, qb, kb, vtmp, nullptr);
    transpose_v<<<dim3(SEQ / 64, DHEAD / 64, NB * NHEADS), 256, 0, stream>>>(vtmp, vT);
    attn_kernel<<<dim3(16 * NB * NHEADS), 256, 0, stream>>>(qb, kb, vT, ctx);
    gemm_expert<1, HID / 128><<<dim3(HID / 128, T_TOKENS / 128, 2), 256, 0, stream>>>(
        ctx, wvdT, wldT, counts, idx, nullptr, nullptr, nullptr, nullptr, out);
}

// Round 11
// 1535.078 us; speedup vs baseline: 1.0001x; 1.0001x over previous
//
#include <hip/hip_runtime.h>
#include <math.h>

#define SEQ     2048
#define NB      2
#define NHEADS  32
#define DHEAD   128
#define HID     4096
#define NQKV    12288
#define T_TOKENS (NB*SEQ)

typedef _Float16 half8 __attribute__((ext_vector_type(8)));
typedef float v4f __attribute__((ext_vector_type(4)));

__device__ __forceinline__ void gload_lds16(const void* g, void* l) {
    __builtin_amdgcn_global_load_lds(
        (__attribute__((address_space(1))) void*)(void*)(g),
        (__attribute__((address_space(3))) void*)(unsigned)(unsigned long long)(l),
        16, 0, 0);
}

__device__ __forceinline__ v4f mfma16(half8 a, half8 b, v4f c) {
    return __builtin_amdgcn_mfma_f32_16x16x32_f16(a, b, c, 0, 0, 0);
}

// ---------------- routing ----------------
__global__ void route_kernel(const int* __restrict__ tt, int* counts, int* idx) {
    int t = blockIdx.x * blockDim.x + threadIdx.x;
    if (t >= T_TOKENS) return;
    int s = t & (SEQ - 1);
    bool vm = (s < SEQ - 1) && (tt[t] == 1) && (tt[t + 1] == 1);
    int e = vm ? 0 : 1;
    int p = atomicAdd(&counts[e], 1);
    idx[e * T_TOKENS + p] = t;
}

// ---------------- RoPE cos/sin table (accurate, once per call) ----------------
__global__ void rope_table_kernel(const int* __restrict__ pos_ids, float2* __restrict__ tab) {
    int i = blockIdx.x * blockDim.x + threadIdx.x;
    if (i >= T_TOKENS * 64) return;
    int tok = i >> 6, j = i & 63;
    float invf = (float)pow(10000.0, -(double)j * (1.0 / 64.0));
    float ang = (float)pos_ids[tok] * invf;
    double ds, dc;
    sincos((double)ang, &ds, &dc);
    tab[i] = make_float2((float)dc, (float)ds);
}

// ---------------- fp32 -> fp16 ----------------
__global__ void cvt_f32_f16(const float* __restrict__ src, _Float16* __restrict__ dst, int n4) {
    int i = blockIdx.x * blockDim.x + threadIdx.x;
    if (i >= n4) return;
    float4 v = ((const float4*)src)[i];
    union { _Float16 h[4]; uint2 u; } p;
    p.h[0] = (_Float16)v.x; p.h[1] = (_Float16)v.y;
    p.h[2] = (_Float16)v.z; p.h[3] = (_Float16)v.w;
    ((uint2*)dst)[i] = p.u;
}

// ---------------- W [K][N] f32 -> WT [N][K] f16 ----------------
__global__ void transpose_cvt(const float* __restrict__ W, _Float16* __restrict__ WT,
                              int K, int N) {
    __shared__ _Float16 t[64][72];
    const int n0 = blockIdx.x * 64, k0 = blockIdx.y * 64;
    const int cr = threadIdx.x & 15, rr = threadIdx.x >> 4;
#pragma unroll
    for (int it = 0; it < 4; ++it) {
        int r = rr + it * 16;
        float4 v = *(const float4*)&W[(size_t)(k0 + r) * N + n0 + cr * 4];
        t[cr*4+0][r] = (_Float16)v.x; t[cr*4+1][r] = (_Float16)v.y;
        t[cr*4+2][r] = (_Float16)v.z; t[cr*4+3][r] = (_Float16)v.w;
    }
    __syncthreads();
#pragma unroll
    for (int it = 0; it < 4; ++it) {
        int r = rr + it * 16;
        union { _Float16 h[4]; uint2 u; } p;
#pragma unroll
        for (int j = 0; j < 4; ++j) p.h[j] = t[r][cr*4+j];
        *(uint2*)&WT[(size_t)(n0 + r) * K + k0 + cr * 4] = p.u;
    }
}

// ---------------- V [b,s,h,d] -> VT [bh][d][s] ----------------
__global__ void transpose_v(const _Float16* __restrict__ vin, _Float16* __restrict__ vout) {
    __shared__ _Float16 t[64][72];
    const int s0 = blockIdx.x * 64;
    const int d0 = blockIdx.y * 64;
    const int bh = blockIdx.z;
    const int b = bh >> 5, h = bh & 31;
    const int cr = threadIdx.x & 15, rr = threadIdx.x >> 4;
#pragma unroll
    for (int it = 0; it < 4; ++it) {
        int sl = rr + it * 16;
        union { _Float16 h4[4]; uint2 u; } p;
        p.u = *(const uint2*)&vin[(size_t)(b * SEQ + s0 + sl) * HID + h * DHEAD + d0 + cr * 4];
#pragma unroll
        for (int j = 0; j < 4; ++j) t[cr*4+j][sl] = p.h4[j];
    }
    __syncthreads();
#pragma unroll
    for (int it = 0; it < 4; ++it) {
        int dl = rr + it * 16;
        union { _Float16 h4[4]; uint2 u; } p;
#pragma unroll
        for (int j = 0; j < 4; ++j) p.h4[j] = t[dl][cr*4+j];
        *(uint2*)&vout[((size_t)bh * DHEAD + d0 + dl) * SEQ + s0 + cr * 4] = p.u;
    }
}

// ---------------- gathered-row expert GEMM (v7: 256x256 tile) ----------------
// MODE 0: qkv + fused RoPE scatter.  MODE 1: dense -> fp32 out.
// A [T][4096] f16, BT [N][4096] f16. Tile 256x256, BK=32, 512 threads,
// 8 waves in 2x4: wave (wm,wn) computes rows wm*128+i*16 (i<8), cols
// (4j+wn)*16 (j<4) -- RoPE pair (d,d+64) = (j,j+1) stays in-wave; tile spans
// 2 heads, h = h0 + (j>>1).
// Pipeline = round-6's proven one, unchanged: 4 LDS buffers (128 KB ->
// 1 block/CU, 8 waves = 2/SIMD, same TLP as round 6), depth-3 counted
// vmcnt(8), single s_barrier per step, stage(kt+3), tail 8->4->0.
// Arithmetic intensity per LDS byte: 256 MFMA vs 12 ds_read/wave per step
// (0.375 reads/MFMA vs 128-tile's 0.5) -- attacks the 34% plateau.
// Same intra-row chunk swizzle (keys unchanged: staging (lane>>3)&3,
// reads (col>>1)&3). K-order identical -> bit-exact vs round-0.
template <int MODE, int NCT>
__global__ __launch_bounds__(512, 2)
void gemm_expert(const _Float16* __restrict__ A,
                 const _Float16* __restrict__ BT0,
                 const _Float16* __restrict__ BT1,
                 const int* __restrict__ counts,
                 const int* __restrict__ idx_all,
                 const float2* __restrict__ rope,
                 _Float16* __restrict__ qbuf,
                 _Float16* __restrict__ kbuf,
                 _Float16* __restrict__ vbuf,
                 float* __restrict__ out) {
    const int e = blockIdx.z;
    const int count = counts[e];

    // ---- locality remap (bijective): f -> (ct, rt); 2-ct chunks x 16 rts ----
    const int f   = blockIdx.x + NCT * blockIdx.y;  // dispatch-order flat id
    const int xcd = f & 7;                          // HW round-robins XCDs
    const int g   = f >> 3;                         // per-XCD sequence
    const int c   = g >> 5;                         // ct-chunk (2 cts x 16 rts)
    const int wi  = g & 31;
    const int rt  = wi >> 1;                        // 0..15
    const int ct  = xcd * (NCT / 8) + c * 2 + (wi & 1);

    if (rt * 256 >= count) return;
    const int* idx = idx_all + e * T_TOKENS;
    const _Float16* BT = e ? BT1 : BT0;

    __shared__ _Float16 sA[4][256 * 32];
    __shared__ _Float16 sB[4][256 * 32];

    const int tid = threadIdx.x;
    const int w = tid >> 6, lane = tid & 63;
    const int col = lane & 15, quad = lane >> 4;
    const int wm = w >> 2, wn = w & 3;

    // staging: wave w stages rows w*32..w*32+31 of A and B (2 ops x 16 rows;
    // 4 loads/thread/stage -> vmcnt(8) = 2 newer stages, same as round 6).
    // row-in-op = lane>>2, chunk = lane&3; swizzle key (row>>1)&3 = (lane>>3)&3.
    const int schk = (lane & 3) ^ ((lane >> 3) & 3);
    const _Float16* ag[2];
    const _Float16* bg[2];
    int so[2];
#pragma unroll
    for (int o = 0; o < 2; ++o) {
        int r = w * 32 + o * 16 + (lane >> 2);
        int gg = rt * 256 + r; if (gg > count - 1) gg = count - 1;
        ag[o] = A + (size_t)idx[gg] * HID + schk * 8;
        bg[o] = BT + (size_t)(ct * 256 + r) * HID + schk * 8;
        so[o] = (w * 32 + o * 16) * 32;
    }

    v4f acc[8][4];
#pragma unroll
    for (int i = 0; i < 8; ++i)
#pragma unroll
        for (int j = 0; j < 4; ++j) { v4f z = {0.f, 0.f, 0.f, 0.f}; acc[i][j] = z; }

    // fragment-read rows are (mult of 16)+col -> swizzle key (col>>1)&3
    const int kofq = (quad ^ ((col >> 1) & 3)) * 8;

    auto stage = [&](int buf) {
#pragma unroll
        for (int o = 0; o < 2; ++o) {
            gload_lds16(ag[o], &sA[buf][so[o]]);
            gload_lds16(bg[o], &sB[buf][so[o]]);
            ag[o] += 32; bg[o] += 32;
        }
    };
    auto compute = [&](int cur) {
        half8 a[8], b[4];
#pragma unroll
        for (int i = 0; i < 8; ++i)
            a[i] = *(const half8*)&sA[cur][(wm * 128 + i * 16 + col) * 32 + kofq];
#pragma unroll
        for (int j = 0; j < 4; ++j)
            b[j] = *(const half8*)&sB[cur][((4 * j + wn) * 16 + col) * 32 + kofq];
#pragma unroll
        for (int i = 0; i < 8; ++i)
#pragma unroll
            for (int j = 0; j < 4; ++j)
                acc[i][j] = mfma16(a[i], b[j], acc[i][j]);
    };

    const int NK = HID / 32;   // 128
    // prologue: 3 stages in flight (12 loads)
    stage(0); stage(1); stage(2);

    for (int kt = 0; kt < NK - 3; ++kt) {
        asm volatile("s_waitcnt vmcnt(8)" ::: "memory");  // stage(kt) retired
        __builtin_amdgcn_s_barrier();                     // cross-wave publish
        asm volatile("" ::: "memory");
        stage((kt + 3) & 3);                              // 12 loads in flight again
        compute(kt & 3);
    }
    // tail: kt = NK-3, NK-2, NK-1 (no more stages; counts drain 8 -> 4 -> 0)
    asm volatile("s_waitcnt vmcnt(8)" ::: "memory");
    __builtin_amdgcn_s_barrier();
    asm volatile("" ::: "memory");
    compute((NK - 3) & 3);
    asm volatile("s_waitcnt vmcnt(4)" ::: "memory");
    __builtin_amdgcn_s_barrier();
    asm volatile("" ::: "memory");
    compute((NK - 2) & 3);
    asm volatile("s_waitcnt vmcnt(0)" ::: "memory");
    __builtin_amdgcn_s_barrier();
    asm volatile("" ::: "memory");
    compute((NK - 1) & 3);

    const int n0 = ct * 256;
    if (MODE == 1) {
#pragma unroll
        for (int i = 0; i < 8; ++i)
#pragma unroll
            for (int r = 0; r < 4; ++r) {
                int rg = rt * 256 + wm * 128 + i * 16 + quad * 4 + r;
                if (rg >= count) continue;
                int tok = idx[rg];
                float* dst = out + (size_t)tok * HID + n0;
#pragma unroll
                for (int j = 0; j < 4; ++j) dst[(4 * j + wn) * 16 + col] = acc[i][j][r];
            }
    } else {
        const int sec = n0 >> 12;          // 0=q 1=k 2=v (4096/256=16: no straddle)
        const int h0 = (n0 >> 7) & 31;     // first head of the 2 this tile spans
#pragma unroll
        for (int i = 0; i < 8; ++i)
#pragma unroll
            for (int r = 0; r < 4; ++r) {
                int rg = rt * 256 + wm * 128 + i * 16 + quad * 4 + r;
                if (rg >= count) continue;
                int tok = idx[rg];
                int b = tok >> 11, s = tok & (SEQ - 1);
                if (sec == 2) {
#pragma unroll
                    for (int j = 0; j < 4; ++j) {
                        int h = (h0 + (j >> 1)) & 31;
                        vbuf[(size_t)tok * HID + h * DHEAD + (j & 1) * 64 + wn * 16 + col] =
                            (_Float16)acc[i][j][r];
                    }
                } else {
                    const float2* tp = rope + (size_t)tok * 64;
                    int d = wn * 16 + col;          // 0..63 within head
                    float2 cs = tp[d];
#pragma unroll
                    for (int jj = 0; jj < 4; jj += 2) {
                        int h = (h0 + (jj >> 1)) & 31;
                        _Float16* dst = (sec ? kbuf : qbuf) +
                            ((size_t)(b * NHEADS + h) * SEQ + s) * DHEAD;
                        float x = acc[i][jj][r], y = acc[i][jj + 1][r];
                        dst[d]      = (_Float16)(x * cs.x - y * cs.y);
                        dst[d + 64] = (_Float16)(y * cs.x + x * cs.y);
                    }
                }
            }
    }
}

// ---------------- flash attention (round-9 version, unchanged) ----------------
// KVBLK=64, double-buffered K/V, dedicated P region (own-wave rows -> no P
// barriers), ONE barrier per kv-tile at iteration end. Next tile's
// global_load_lds issued BEFORE compute so HBM/L2 latency hides under
// QK+softmax+PV (T3-minimum). LDS 80KB -> 2 blocks/CU. setprio around MFMA.
__global__ __launch_bounds__(256, 2)
void attn_kernel(const _Float16* __restrict__ qbuf,
                 const _Float16* __restrict__ kbuf,
                 const _Float16* __restrict__ vt,
                 _Float16* __restrict__ ctx) {
    // XCD-aware decode of flat block id: all 16 q-tiles of a head on one XCD,
    // qt paired u/15-u across co-resident rounds for load balance.
    const int f   = blockIdx.x;            // 0..1023
    const int xcd = f & 7;
    const int t   = f >> 3;
    const int s   = t & 31;
    const int rr  = t >> 5;
    const int u   = s & 15, g = s >> 4;
    const int bh  = xcd * 8 + rr * 2 + g;
    const int qt  = (rr & 1) ? (15 - u) : u;

    const int b = bh >> 5, h = bh & 31;
    const int tid = threadIdx.x;
    const int w = tid >> 6, lane = tid & 63;
    const int col = lane & 15, quad = lane >> 4;

    __shared__ _Float16 sK[2][64 * 128];   // K [64][128], swizzled, double-buffered
    __shared__ _Float16 sV[2][128 * 64];   // V [d=128][s=64], swizzled, double-buffered
    __shared__ _Float16 sP[128 * 64];      // P [128][64], swizzled, per-wave rows

    half8 qf[2][4];
    const _Float16 qscale = (_Float16)0.08838834764831845f;  // 1/sqrt(128)
#pragma unroll
    for (int mt = 0; mt < 2; ++mt)
#pragma unroll
        for (int kc = 0; kc < 4; ++kc) {
            int row = qt * 128 + w * 32 + mt * 16 + col;
            half8 v = *(const half8*)&qbuf[((size_t)bh * SEQ + row) * DHEAD + kc * 32 + quad * 8];
            qf[mt][kc] = v * qscale;
        }

    float mrow[2][4], lrow[2][4];
    v4f o[2][8];
#pragma unroll
    for (int mt = 0; mt < 2; ++mt)
#pragma unroll
        for (int r = 0; r < 4; ++r) { mrow[mt][r] = -3.0e38f; lrow[mt][r] = 0.f; }
#pragma unroll
    for (int i = 0; i < 2; ++i)
#pragma unroll
        for (int j = 0; j < 8; ++j) { v4f z = {0.f, 0.f, 0.f, 0.f}; o[i][j] = z; }

    const int cxor = col & 7;
    const int vs_chk = (lane & 7) ^ (lane >> 3);
    const int nkt = 2 * qt + 2;

    const _Float16* kg0 = kbuf + (size_t)bh * SEQ * DHEAD;
    const _Float16* vg0 = vt + (size_t)bh * DHEAD * SEQ;

    auto stage = [&](int kt, int buf) {
        const _Float16* kg = kg0 + (size_t)kt * 64 * DHEAD;
        const _Float16* vg = vg0 + kt * 64;
#pragma unroll
        for (int op = 0; op < 4; ++op) {
            int r0 = (w * 4 + op) * 4;            // K: 4 rows x 16 chunks per op
            int krow = r0 + quad;
            int kcs = col ^ (krow & 7);
            gload_lds16(kg + (size_t)krow * DHEAD + kcs * 8, &sK[buf][r0 * 128]);
            int d0 = (w * 4 + op) * 8;            // V: 8 rows x 8 chunks per op
            int vrow = d0 + (lane >> 3);
            gload_lds16(vg + (size_t)vrow * SEQ + vs_chk * 8, &sV[buf][d0 * 64]);
        }
    };

    stage(0, 0);
    __syncthreads();   // drain prologue stage

    for (int kt = 0; kt < nkt; ++kt) {
        const int cur = kt & 1;
        // issue next tile's loads first -- they complete during compute below
        if (kt + 1 < nkt) stage(kt + 1, cur ^ 1);

        v4f sc[2][4];
#pragma unroll
        for (int i = 0; i < 2; ++i)
#pragma unroll
            for (int j = 0; j < 4; ++j) { v4f z = {0.f, 0.f, 0.f, 0.f}; sc[i][j] = z; }
        __builtin_amdgcn_s_setprio(1);
#pragma unroll
        for (int kc = 0; kc < 4; ++kc) {
            const int kof = ((kc * 4 + quad) ^ cxor) * 8;
#pragma unroll
            for (int nt = 0; nt < 4; ++nt) {
                half8 bf = *(const half8*)&sK[cur][(size_t)(nt * 16 + col) * 128 + kof];
                sc[0][nt] = mfma16(qf[0][kc], bf, sc[0][nt]);
                sc[1][nt] = mfma16(qf[1][kc], bf, sc[1][nt]);
            }
        }
        __builtin_amdgcn_s_setprio(0);

        if (kt >= 2 * qt) {   // only the last two tiles touch the diagonal
#pragma unroll
            for (int mt = 0; mt < 2; ++mt)
#pragma unroll
                for (int nt = 0; nt < 4; ++nt)
#pragma unroll
                    for (int r = 0; r < 4; ++r) {
                        int rowa = qt * 128 + w * 32 + mt * 16 + quad * 4 + r;
                        int cola = kt * 64 + nt * 16 + col;
                        if (cola > rowa) sc[mt][nt][r] = -3.0e38f;
                    }
        }

#pragma unroll
        for (int mt = 0; mt < 2; ++mt)
#pragma unroll
            for (int r = 0; r < 4; ++r) {
                float mx = sc[mt][0][r];
#pragma unroll
                for (int nt = 1; nt < 4; ++nt) mx = fmaxf(mx, sc[mt][nt][r]);
                mx = fmaxf(mx, __shfl_xor(mx, 1));
                mx = fmaxf(mx, __shfl_xor(mx, 2));
                mx = fmaxf(mx, __shfl_xor(mx, 4));
                mx = fmaxf(mx, __shfl_xor(mx, 8));
                float newm = fmaxf(mrow[mt][r], mx);
                float alpha = __expf(mrow[mt][r] - newm);
                mrow[mt][r] = newm;
                float rs = 0.f;
#pragma unroll
                for (int nt = 0; nt < 4; ++nt) {
                    float p = __expf(sc[mt][nt][r] - newm);
                    sc[mt][nt][r] = p;
                    rs += p;
                }
                rs += __shfl_xor(rs, 1); rs += __shfl_xor(rs, 2);
                rs += __shfl_xor(rs, 4); rs += __shfl_xor(rs, 8);
                lrow[mt][r] = lrow[mt][r] * alpha + rs;
#pragma unroll
                for (int nt = 0; nt < 8; ++nt) o[mt][nt][r] *= alpha;
            }

        // P -> sP (each wave owns rows w*32..w*32+31: no cross-wave barrier)
#pragma unroll
        for (int mt = 0; mt < 2; ++mt)
#pragma unroll
            for (int nt = 0; nt < 4; ++nt)
#pragma unroll
                for (int r = 0; r < 4; ++r) {
                    int rp = w * 32 + mt * 16 + quad * 4 + r;
                    int colh = nt * 16 + col;
                    int c = (colh >> 3) ^ (rp & 7);
                    sP[(size_t)rp * 64 + c * 8 + (colh & 7)] = (_Float16)sc[mt][nt][r];
                }

        __builtin_amdgcn_s_setprio(1);
#pragma unroll
        for (int kc = 0; kc < 2; ++kc) {
            const int kof = ((kc * 4 + quad) ^ cxor) * 8;
            half8 p0 = *(const half8*)&sP[(size_t)(w * 32 + col) * 64 + kof];
            half8 p1 = *(const half8*)&sP[(size_t)(w * 32 + 16 + col) * 64 + kof];
#pragma unroll
            for (int nt = 0; nt < 8; ++nt) {
                half8 vf = *(const half8*)&sV[cur][(size_t)(nt * 16 + col) * 64 + kof];
                o[0][nt] = mfma16(p0, vf, o[0][nt]);
                o[1][nt] = mfma16(p1, vf, o[1][nt]);
            }
        }
        __builtin_amdgcn_s_setprio(0);

        // single barrier: drains next-tile stage (vmcnt) + guards K/V reuse
        __syncthreads();
    }

#pragma unroll
    for (int mt = 0; mt < 2; ++mt)
#pragma unroll
        for (int r = 0; r < 4; ++r) {
            int rowa = qt * 128 + w * 32 + mt * 16 + quad * 4 + r;
            float inv = 1.0f / lrow[mt][r];
            _Float16* dst = ctx + ((size_t)b * SEQ + rowa) * HID + h * DHEAD;
#pragma unroll
            for (int nt = 0; nt < 8; ++nt)
                dst[nt * 16 + col] = (_Float16)(o[mt][nt][r] * inv);
        }
}

extern "C" void kernel_launch(void* const* d_in, const int* in_sizes, int n_in,
                              void* d_out, int out_size, void* d_ws, size_t ws_size,
                              hipStream_t stream) {
    const float* hidden = (const float*)d_in[0];
    const int*   tt     = (const int*)d_in[1];
    const int*   pos    = (const int*)d_in[2];
    const float* wvq    = (const float*)d_in[3];
    const float* wlq    = (const float*)d_in[4];
    const float* wvd    = (const float*)d_in[5];
    const float* wld    = (const float*)d_in[6];
    float* out = (float*)d_out;

    char* ws = (char*)d_ws;
    size_t off = 0;
    auto alloc = [&](size_t bytes) {
        char* p = ws + off;
        off += (bytes + 255) & ~(size_t)255;
        return p;
    };
    const size_t TOKB = (size_t)T_TOKENS * HID * sizeof(_Float16);  // 33.5 MB
    _Float16* h16  = (_Float16*)alloc(TOKB);                        // later reused as vT
    _Float16* wvqT = (_Float16*)alloc((size_t)NQKV * HID * 2);
    _Float16* wlqT = (_Float16*)alloc((size_t)NQKV * HID * 2);
    _Float16* wvdT = (_Float16*)alloc((size_t)HID * HID * 2);
    _Float16* wldT = (_Float16*)alloc((size_t)HID * HID * 2);
    _Float16* qb   = (_Float16*)alloc(TOKB);
    _Float16* kb   = (_Float16*)alloc(TOKB);
    _Float16* vtmp = (_Float16*)alloc(TOKB);                        // later reused as ctx
    int* counts = (int*)alloc(2 * sizeof(int));
    int* idx    = (int*)alloc(2 * T_TOKENS * sizeof(int));
    float2* rope = (float2*)alloc((size_t)T_TOKENS * 64 * sizeof(float2));
    _Float16* vT  = h16;    // hidden16 dead after QKV GEMM
    _Float16* ctx = vtmp;   // v token-major dead after transpose_v

    hipMemsetAsync(counts, 0, 2 * sizeof(int), stream);
    route_kernel<<<T_TOKENS / 256, 256, 0, stream>>>(tt, counts, idx);
    rope_table_kernel<<<(T_TOKENS * 64) / 256, 256, 0, stream>>>(pos, rope);
    cvt_f32_f16<<<(T_TOKENS * HID / 4) / 256, 256, 0, stream>>>(hidden, h16, T_TOKENS * HID / 4);
    transpose_cvt<<<dim3(NQKV / 64, HID / 64), 256, 0, stream>>>(wvq, wvqT, HID, NQKV);
    transpose_cvt<<<dim3(NQKV / 64, HID / 64), 256, 0, stream>>>(wlq, wlqT, HID, NQKV);
    transpose_cvt<<<dim3(HID / 64, HID / 64), 256, 0, stream>>>(wvd, wvdT, HID, HID);
    transpose_cvt<<<dim3(HID / 64, HID / 64), 256, 0, stream>>>(wld, wldT, HID, HID);
    gemm_expert<0, NQKV / 256><<<dim3(NQKV / 256, T_TOKENS / 256, 2), 512, 0, stream>>>(
        h16, wvqT, wlqT, counts, idx, rope, qb, kb, vtmp, nullptr);
    transpose_v<<<dim3(SEQ / 64, DHEAD / 64, NB * NHEADS), 256, 0, stream>>>(vtmp, vT);
    attn_kernel<<<dim3(16 * NB * NHEADS), 256, 0, stream>>>(qb, kb, vT, ctx);
    gemm_expert<1, HID / 256><<<dim3(HID / 256, T_TOKENS / 256, 2), 512, 0, stream>>>(
        ctx, wvdT, wldT, counts, idx, nullptr, nullptr, nullptr, nullptr, out);
}

// Round 12
// 1499.464 us; speedup vs baseline: 1.0238x; 1.0238x over previous
//
#include <hip/hip_runtime.h>
#include <math.h>

#define SEQ     2048
#define NB      2
#define NHEADS  32
#define DHEAD   128
#define HID     4096
#define NQKV    12288
#define T_TOKENS (NB*SEQ)

typedef _Float16 half8 __attribute__((ext_vector_type(8)));
typedef float v4f __attribute__((ext_vector_type(4)));

__device__ __forceinline__ void gload_lds16(const void* g, void* l) {
    __builtin_amdgcn_global_load_lds(
        (__attribute__((address_space(1))) void*)(void*)(g),
        (__attribute__((address_space(3))) void*)(unsigned)(unsigned long long)(l),
        16, 0, 0);
}

__device__ __forceinline__ v4f mfma16(half8 a, half8 b, v4f c) {
    return __builtin_amdgcn_mfma_f32_16x16x32_f16(a, b, c, 0, 0, 0);
}

// ---------------- routing ----------------
__global__ void route_kernel(const int* __restrict__ tt, int* counts, int* idx) {
    int t = blockIdx.x * blockDim.x + threadIdx.x;
    if (t >= T_TOKENS) return;
    int s = t & (SEQ - 1);
    bool vm = (s < SEQ - 1) && (tt[t] == 1) && (tt[t + 1] == 1);
    int e = vm ? 0 : 1;
    int p = atomicAdd(&counts[e], 1);
    idx[e * T_TOKENS + p] = t;
}

// ---------------- RoPE cos/sin table (accurate, once per call) ----------------
__global__ void rope_table_kernel(const int* __restrict__ pos_ids, float2* __restrict__ tab) {
    int i = blockIdx.x * blockDim.x + threadIdx.x;
    if (i >= T_TOKENS * 64) return;
    int tok = i >> 6, j = i & 63;
    float invf = (float)pow(10000.0, -(double)j * (1.0 / 64.0));
    float ang = (float)pos_ids[tok] * invf;
    double ds, dc;
    sincos((double)ang, &ds, &dc);
    tab[i] = make_float2((float)dc, (float)ds);
}

// ---------------- fp32 -> fp16 ----------------
__global__ void cvt_f32_f16(const float* __restrict__ src, _Float16* __restrict__ dst, int n4) {
    int i = blockIdx.x * blockDim.x + threadIdx.x;
    if (i >= n4) return;
    float4 v = ((const float4*)src)[i];
    union { _Float16 h[4]; uint2 u; } p;
    p.h[0] = (_Float16)v.x; p.h[1] = (_Float16)v.y;
    p.h[2] = (_Float16)v.z; p.h[3] = (_Float16)v.w;
    ((uint2*)dst)[i] = p.u;
}

// ---------------- W [K][N] f32 -> WT [N][K] f16 ----------------
__global__ void transpose_cvt(const float* __restrict__ W, _Float16* __restrict__ WT,
                              int K, int N) {
    __shared__ _Float16 t[64][72];
    const int n0 = blockIdx.x * 64, k0 = blockIdx.y * 64;
    const int cr = threadIdx.x & 15, rr = threadIdx.x >> 4;
#pragma unroll
    for (int it = 0; it < 4; ++it) {
        int r = rr + it * 16;
        float4 v = *(const float4*)&W[(size_t)(k0 + r) * N + n0 + cr * 4];
        t[cr*4+0][r] = (_Float16)v.x; t[cr*4+1][r] = (_Float16)v.y;
        t[cr*4+2][r] = (_Float16)v.z; t[cr*4+3][r] = (_Float16)v.w;
    }
    __syncthreads();
#pragma unroll
    for (int it = 0; it < 4; ++it) {
        int r = rr + it * 16;
        union { _Float16 h[4]; uint2 u; } p;
#pragma unroll
        for (int j = 0; j < 4; ++j) p.h[j] = t[r][cr*4+j];
        *(uint2*)&WT[(size_t)(n0 + r) * K + k0 + cr * 4] = p.u;
    }
}

// ---------------- V [b,s,h,d] -> VT [bh][d][s] ----------------
__global__ void transpose_v(const _Float16* __restrict__ vin, _Float16* __restrict__ vout) {
    __shared__ _Float16 t[64][72];
    const int s0 = blockIdx.x * 64;
    const int d0 = blockIdx.y * 64;
    const int bh = blockIdx.z;
    const int b = bh >> 5, h = bh & 31;
    const int cr = threadIdx.x & 15, rr = threadIdx.x >> 4;
#pragma unroll
    for (int it = 0; it < 4; ++it) {
        int sl = rr + it * 16;
        union { _Float16 h4[4]; uint2 u; } p;
        p.u = *(const uint2*)&vin[(size_t)(b * SEQ + s0 + sl) * HID + h * DHEAD + d0 + cr * 4];
#pragma unroll
        for (int j = 0; j < 4; ++j) t[cr*4+j][sl] = p.h4[j];
    }
    __syncthreads();
#pragma unroll
    for (int it = 0; it < 4; ++it) {
        int dl = rr + it * 16;
        union { _Float16 h4[4]; uint2 u; } p;
#pragma unroll
        for (int j = 0; j < 4; ++j) p.h4[j] = t[dl][cr*4+j];
        *(uint2*)&vout[((size_t)bh * DHEAD + d0 + dl) * SEQ + s0 + cr * 4] = p.u;
    }
}

// ---------------- gathered-row expert GEMM, 256x256 tile (MODE 0) ----------------
// Round-11 measured version, verbatim: 512 threads, 8 waves 2x4, BK=32,
// depth-3 counted-vmcnt(8) pipeline, 4 LDS buffers (128 KB), intra-row chunk
// swizzle. FETCH halved vs 128-tile; MfmaUtil 36.2.
template <int MODE, int NCT>
__global__ __launch_bounds__(512, 2)
void gemm_expert256(const _Float16* __restrict__ A,
                    const _Float16* __restrict__ BT0,
                    const _Float16* __restrict__ BT1,
                    const int* __restrict__ counts,
                    const int* __restrict__ idx_all,
                    const float2* __restrict__ rope,
                    _Float16* __restrict__ qbuf,
                    _Float16* __restrict__ kbuf,
                    _Float16* __restrict__ vbuf,
                    float* __restrict__ out) {
    const int e = blockIdx.z;
    const int count = counts[e];

    const int f   = blockIdx.x + NCT * blockIdx.y;
    const int xcd = f & 7;
    const int g   = f >> 3;
    const int c   = g >> 5;
    const int wi  = g & 31;
    const int rt  = wi >> 1;
    const int ct  = xcd * (NCT / 8) + c * 2 + (wi & 1);

    if (rt * 256 >= count) return;
    const int* idx = idx_all + e * T_TOKENS;
    const _Float16* BT = e ? BT1 : BT0;

    __shared__ _Float16 sA[4][256 * 32];
    __shared__ _Float16 sB[4][256 * 32];

    const int tid = threadIdx.x;
    const int w = tid >> 6, lane = tid & 63;
    const int col = lane & 15, quad = lane >> 4;
    const int wm = w >> 2, wn = w & 3;

    const int schk = (lane & 3) ^ ((lane >> 3) & 3);
    const _Float16* ag[2];
    const _Float16* bg[2];
    int so[2];
#pragma unroll
    for (int o = 0; o < 2; ++o) {
        int r = w * 32 + o * 16 + (lane >> 2);
        int gg = rt * 256 + r; if (gg > count - 1) gg = count - 1;
        ag[o] = A + (size_t)idx[gg] * HID + schk * 8;
        bg[o] = BT + (size_t)(ct * 256 + r) * HID + schk * 8;
        so[o] = (w * 32 + o * 16) * 32;
    }

    v4f acc[8][4];
#pragma unroll
    for (int i = 0; i < 8; ++i)
#pragma unroll
        for (int j = 0; j < 4; ++j) { v4f z = {0.f, 0.f, 0.f, 0.f}; acc[i][j] = z; }

    const int kofq = (quad ^ ((col >> 1) & 3)) * 8;

    auto stage = [&](int buf) {
#pragma unroll
        for (int o = 0; o < 2; ++o) {
            gload_lds16(ag[o], &sA[buf][so[o]]);
            gload_lds16(bg[o], &sB[buf][so[o]]);
            ag[o] += 32; bg[o] += 32;
        }
    };
    auto compute = [&](int cur) {
        half8 a[8], b[4];
#pragma unroll
        for (int i = 0; i < 8; ++i)
            a[i] = *(const half8*)&sA[cur][(wm * 128 + i * 16 + col) * 32 + kofq];
#pragma unroll
        for (int j = 0; j < 4; ++j)
            b[j] = *(const half8*)&sB[cur][((4 * j + wn) * 16 + col) * 32 + kofq];
#pragma unroll
        for (int i = 0; i < 8; ++i)
#pragma unroll
            for (int j = 0; j < 4; ++j)
                acc[i][j] = mfma16(a[i], b[j], acc[i][j]);
    };

    const int NK = HID / 32;
    stage(0); stage(1); stage(2);

    for (int kt = 0; kt < NK - 3; ++kt) {
        asm volatile("s_waitcnt vmcnt(8)" ::: "memory");
        __builtin_amdgcn_s_barrier();
        asm volatile("" ::: "memory");
        stage((kt + 3) & 3);
        compute(kt & 3);
    }
    asm volatile("s_waitcnt vmcnt(8)" ::: "memory");
    __builtin_amdgcn_s_barrier();
    asm volatile("" ::: "memory");
    compute((NK - 3) & 3);
    asm volatile("s_waitcnt vmcnt(4)" ::: "memory");
    __builtin_amdgcn_s_barrier();
    asm volatile("" ::: "memory");
    compute((NK - 2) & 3);
    asm volatile("s_waitcnt vmcnt(0)" ::: "memory");
    __builtin_amdgcn_s_barrier();
    asm volatile("" ::: "memory");
    compute((NK - 1) & 3);

    const int n0 = ct * 256;
    if (MODE == 1) {
#pragma unroll
        for (int i = 0; i < 8; ++i)
#pragma unroll
            for (int r = 0; r < 4; ++r) {
                int rg = rt * 256 + wm * 128 + i * 16 + quad * 4 + r;
                if (rg >= count) continue;
                int tok = idx[rg];
                float* dst = out + (size_t)tok * HID + n0;
#pragma unroll
                for (int j = 0; j < 4; ++j) dst[(4 * j + wn) * 16 + col] = acc[i][j][r];
            }
    } else {
        const int sec = n0 >> 12;
        const int h0 = (n0 >> 7) & 31;
#pragma unroll
        for (int i = 0; i < 8; ++i)
#pragma unroll
            for (int r = 0; r < 4; ++r) {
                int rg = rt * 256 + wm * 128 + i * 16 + quad * 4 + r;
                if (rg >= count) continue;
                int tok = idx[rg];
                int b = tok >> 11, s = tok & (SEQ - 1);
                if (sec == 2) {
#pragma unroll
                    for (int j = 0; j < 4; ++j) {
                        int h = (h0 + (j >> 1)) & 31;
                        vbuf[(size_t)tok * HID + h * DHEAD + (j & 1) * 64 + wn * 16 + col] =
                            (_Float16)acc[i][j][r];
                    }
                } else {
                    const float2* tp = rope + (size_t)tok * 64;
                    int d = wn * 16 + col;
                    float2 cs = tp[d];
#pragma unroll
                    for (int jj = 0; jj < 4; jj += 2) {
                        int h = (h0 + (jj >> 1)) & 31;
                        _Float16* dst = (sec ? kbuf : qbuf) +
                            ((size_t)(b * NHEADS + h) * SEQ + s) * DHEAD;
                        float x = acc[i][jj][r], y = acc[i][jj + 1][r];
                        dst[d]      = (_Float16)(x * cs.x - y * cs.y);
                        dst[d + 64] = (_Float16)(y * cs.x + x * cs.y);
                    }
                }
            }
    }
}

// ---------------- gathered-row expert GEMM, 128x128 tile (MODE 1) ----------------
// Round-6/9 measured version, verbatim: BK=32, 4 waves stacked in M, depth-3
// counted-vmcnt(8) pipeline, 4 LDS buffers, intra-row chunk swizzle.
template <int MODE, int NCT>
__global__ __launch_bounds__(256, 2)
void gemm_expert128(const _Float16* __restrict__ A,
                    const _Float16* __restrict__ BT0,
                    const _Float16* __restrict__ BT1,
                    const int* __restrict__ counts,
                    const int* __restrict__ idx_all,
                    const float2* __restrict__ rope,
                    _Float16* __restrict__ qbuf,
                    _Float16* __restrict__ kbuf,
                    _Float16* __restrict__ vbuf,
                    float* __restrict__ out) {
    const int e = blockIdx.z;
    const int count = counts[e];

    const int f   = blockIdx.x + NCT * blockIdx.y;
    const int xcd = f & 7;
    const int g   = f >> 3;
    const int c   = g >> 6;
    const int wi  = g & 63;
    const int rt  = wi >> 1;
    const int ct  = xcd * (NCT / 8) + c * 2 + (wi & 1);

    if (rt * 128 >= count) return;
    const int* idx = idx_all + e * T_TOKENS;
    const _Float16* BT = e ? BT1 : BT0;

    __shared__ _Float16 sA[4][128 * 32];
    __shared__ _Float16 sB[4][128 * 32];

    const int tid = threadIdx.x;
    const int w = tid >> 6, lane = tid & 63;
    const int col = lane & 15, quad = lane >> 4;

    const int r0 = (w * 2 + 0) * 16 + (lane >> 2);
    const int r1 = (w * 2 + 1) * 16 + (lane >> 2);
    int g0 = rt * 128 + r0; if (g0 > count - 1) g0 = count - 1;
    int g1 = rt * 128 + r1; if (g1 > count - 1) g1 = count - 1;
    const int tok0 = idx[g0], tok1 = idx[g1];
    const int schk = (lane & 3) ^ ((lane >> 3) & 3);
    const _Float16* ag0 = A + (size_t)tok0 * HID + schk * 8;
    const _Float16* ag1 = A + (size_t)tok1 * HID + schk * 8;
    const _Float16* bg0 = BT + (size_t)(ct * 128 + r0) * HID + schk * 8;
    const _Float16* bg1 = BT + (size_t)(ct * 128 + r1) * HID + schk * 8;
    const int sa_off0 = (w * 2 + 0) * 512;
    const int sa_off1 = (w * 2 + 1) * 512;

    v4f acc[2][8];
#pragma unroll
    for (int i = 0; i < 2; ++i)
#pragma unroll
        for (int j = 0; j < 8; ++j) { v4f z = {0.f, 0.f, 0.f, 0.f}; acc[i][j] = z; }

    const int kofq = (quad ^ ((col >> 1) & 3)) * 8;
    const int am0 = (w * 32 + col) * 32 + kofq;
    const int am1 = am0 + 16 * 32;

    auto stage = [&](int buf) {
        gload_lds16(ag0, &sA[buf][sa_off0]); gload_lds16(ag1, &sA[buf][sa_off1]);
        gload_lds16(bg0, &sB[buf][sa_off0]); gload_lds16(bg1, &sB[buf][sa_off1]);
        ag0 += 32; ag1 += 32; bg0 += 32; bg1 += 32;
    };
    auto compute = [&](int cur) {
        half8 a0 = *(const half8*)&sA[cur][am0];
        half8 a1 = *(const half8*)&sA[cur][am1];
#pragma unroll
        for (int nt = 0; nt < 8; ++nt) {
            half8 b = *(const half8*)&sB[cur][(nt * 16 + col) * 32 + kofq];
            acc[0][nt] = mfma16(a0, b, acc[0][nt]);
            acc[1][nt] = mfma16(a1, b, acc[1][nt]);
        }
    };

    const int NK = HID / 32;
    stage(0); stage(1); stage(2);

    for (int kt = 0; kt < NK - 3; ++kt) {
        asm volatile("s_waitcnt vmcnt(8)" ::: "memory");
        __builtin_amdgcn_s_barrier();
        asm volatile("" ::: "memory");
        stage((kt + 3) & 3);
        compute(kt & 3);
    }
    asm volatile("s_waitcnt vmcnt(8)" ::: "memory");
    __builtin_amdgcn_s_barrier();
    asm volatile("" ::: "memory");
    compute((NK - 3) & 3);
    asm volatile("s_waitcnt vmcnt(4)" ::: "memory");
    __builtin_amdgcn_s_barrier();
    asm volatile("" ::: "memory");
    compute((NK - 2) & 3);
    asm volatile("s_waitcnt vmcnt(0)" ::: "memory");
    __builtin_amdgcn_s_barrier();
    asm volatile("" ::: "memory");
    compute((NK - 1) & 3);

    const int n0 = ct * 128;
    if (MODE == 1) {
#pragma unroll
        for (int mt = 0; mt < 2; ++mt)
#pragma unroll
            for (int r = 0; r < 4; ++r) {
                int rg = rt * 128 + w * 32 + mt * 16 + quad * 4 + r;
                if (rg >= count) continue;
                int tok = idx[rg];
                float* dst = out + (size_t)tok * HID + n0;
#pragma unroll
                for (int nt = 0; nt < 8; ++nt) dst[nt * 16 + col] = acc[mt][nt][r];
            }
    } else {
        const int sec = n0 >> 12;
        const int h = (n0 >> 7) & 31;
#pragma unroll
        for (int mt = 0; mt < 2; ++mt)
#pragma unroll
            for (int r = 0; r < 4; ++r) {
                int rg = rt * 128 + w * 32 + mt * 16 + quad * 4 + r;
                if (rg >= count) continue;
                int tok = idx[rg];
                int b = tok >> 11, s = tok & (SEQ - 1);
                if (sec == 2) {
                    _Float16* dst = vbuf + (size_t)tok * HID + h * DHEAD;
#pragma unroll
                    for (int nt = 0; nt < 8; ++nt) dst[nt * 16 + col] = (_Float16)acc[mt][nt][r];
                } else {
                    _Float16* dst = (sec ? kbuf : qbuf) + ((size_t)(b * NHEADS + h) * SEQ + s) * DHEAD;
                    const float2* tp = rope + (size_t)tok * 64;
#pragma unroll
                    for (int nt = 0; nt < 4; ++nt) {
                        int d = nt * 16 + col;
                        float2 cs = tp[d];
                        float x = acc[mt][nt][r], y = acc[mt][nt + 4][r];
                        dst[d]      = (_Float16)(x * cs.x - y * cs.y);
                        dst[d + 64] = (_Float16)(y * cs.x + x * cs.y);
                    }
                }
            }
    }
}

// ---------------- flash attention (v5: 8-wave QBLK=256) ----------------
// One block = 256 q-rows (8 waves x 32 rows), 512 threads, 1 block/CU
// (LDS 96KB). Per-wave state identical to the proven round-9 kernel (no
// register growth -- the round-8 lesson). K/V staged ONCE per kv-tile for
// 256 q-rows: K/V fetch + staging per CU HALVED vs 128-row blocks.
// Same prefetch loop, same swizzles, single barrier per tile. Per-wave
// early-skip of fully-masked tiles (barrier still hit by all).
__global__ __launch_bounds__(512, 1)
void attn_kernel(const _Float16* __restrict__ qbuf,
                 const _Float16* __restrict__ kbuf,
                 const _Float16* __restrict__ vt,
                 _Float16* __restrict__ ctx) {
    // XCD-aware decode: 8 heads x 8 q-tiles per XCD; qt paired u/7-u across
    // the two co-residency generations for load balance (36 tiles/CU).
    const int f   = blockIdx.x;            // 0..511
    const int xcd = f & 7;
    const int t   = f >> 3;                // 0..63
    const int rr  = t >> 5;                // generation 0..1
    const int s   = t & 31;
    const int u   = s & 3;
    const int bh  = xcd * 8 + (s >> 2);
    const int qt  = rr ? (7 - u) : u;      // 0..7 (256-row q tiles)

    const int b = bh >> 5, h = bh & 31;
    const int tid = threadIdx.x;
    const int w = tid >> 6, lane = tid & 63;   // w 0..7
    const int col = lane & 15, quad = lane >> 4;

    __shared__ _Float16 sK[2][64 * 128];   // K [64][128], swizzled, double-buffered
    __shared__ _Float16 sV[2][128 * 64];   // V [d=128][s=64], swizzled, double-buffered
    __shared__ _Float16 sP[256 * 64];      // P [256][64], swizzled, per-wave rows

    half8 qf[2][4];
    const _Float16 qscale = (_Float16)0.08838834764831845f;  // 1/sqrt(128)
#pragma unroll
    for (int mt = 0; mt < 2; ++mt)
#pragma unroll
        for (int kc = 0; kc < 4; ++kc) {
            int row = qt * 256 + w * 32 + mt * 16 + col;
            half8 v = *(const half8*)&qbuf[((size_t)bh * SEQ + row) * DHEAD + kc * 32 + quad * 8];
            qf[mt][kc] = v * qscale;
        }

    float mrow[2][4], lrow[2][4];
    v4f o[2][8];
#pragma unroll
    for (int mt = 0; mt < 2; ++mt)
#pragma unroll
        for (int r = 0; r < 4; ++r) { mrow[mt][r] = -3.0e38f; lrow[mt][r] = 0.f; }
#pragma unroll
    for (int i = 0; i < 2; ++i)
#pragma unroll
        for (int j = 0; j < 8; ++j) { v4f z = {0.f, 0.f, 0.f, 0.f}; o[i][j] = z; }

    const int cxor = col & 7;
    const int vs_chk = (lane & 7) ^ (lane >> 3);
    const int nkt = 4 * qt + 4;
    const int rowbase = qt * 256 + w * 32;     // this wave's first q-row

    const _Float16* kg0 = kbuf + (size_t)bh * SEQ * DHEAD;
    const _Float16* vg0 = vt + (size_t)bh * DHEAD * SEQ;

    // staging split over 8 waves: 2 ops each (K: 4 rows x 16 chunks,
    // V: 8 rows x 8 chunks per op). 4 loads/thread/stage.
    auto stage = [&](int kt, int buf) {
        const _Float16* kg = kg0 + (size_t)kt * 64 * DHEAD;
        const _Float16* vg = vg0 + kt * 64;
#pragma unroll
        for (int op = 0; op < 2; ++op) {
            int r0 = (w * 2 + op) * 4;
            int krow = r0 + quad;
            int kcs = col ^ (krow & 7);
            gload_lds16(kg + (size_t)krow * DHEAD + kcs * 8, &sK[buf][r0 * 128]);
            int d0 = (w * 2 + op) * 8;
            int vrow = d0 + (lane >> 3);
            gload_lds16(vg + (size_t)vrow * SEQ + vs_chk * 8, &sV[buf][d0 * 64]);
        }
    };

    stage(0, 0);
    __syncthreads();   // drain prologue stage

    for (int kt = 0; kt < nkt; ++kt) {
        const int cur = kt & 1;
        if (kt + 1 < nkt) stage(kt + 1, cur ^ 1);   // prefetch under compute

        // per-wave early skip: tile fully above the diagonal for ALL of this
        // wave's rows (min cola > max rowa) -> contributes nothing.
        if (kt * 64 <= rowbase + 31) {
            v4f sc[2][4];
#pragma unroll
            for (int i = 0; i < 2; ++i)
#pragma unroll
                for (int j = 0; j < 4; ++j) { v4f z = {0.f, 0.f, 0.f, 0.f}; sc[i][j] = z; }
            __builtin_amdgcn_s_setprio(1);
#pragma unroll
            for (int kc = 0; kc < 4; ++kc) {
                const int kof = ((kc * 4 + quad) ^ cxor) * 8;
#pragma unroll
                for (int nt = 0; nt < 4; ++nt) {
                    half8 bf = *(const half8*)&sK[cur][(size_t)(nt * 16 + col) * 128 + kof];
                    sc[0][nt] = mfma16(qf[0][kc], bf, sc[0][nt]);
                    sc[1][nt] = mfma16(qf[1][kc], bf, sc[1][nt]);
                }
            }
            __builtin_amdgcn_s_setprio(0);

            if (kt * 64 + 63 > rowbase) {   // tile touches this wave's diagonal
#pragma unroll
                for (int mt = 0; mt < 2; ++mt)
#pragma unroll
                    for (int nt = 0; nt < 4; ++nt)
#pragma unroll
                        for (int r = 0; r < 4; ++r) {
                            int rowa = rowbase + mt * 16 + quad * 4 + r;
                            int cola = kt * 64 + nt * 16 + col;
                            if (cola > rowa) sc[mt][nt][r] = -3.0e38f;
                        }
            }

#pragma unroll
            for (int mt = 0; mt < 2; ++mt)
#pragma unroll
                for (int r = 0; r < 4; ++r) {
                    float mx = sc[mt][0][r];
#pragma unroll
                    for (int nt = 1; nt < 4; ++nt) mx = fmaxf(mx, sc[mt][nt][r]);
                    mx = fmaxf(mx, __shfl_xor(mx, 1));
                    mx = fmaxf(mx, __shfl_xor(mx, 2));
                    mx = fmaxf(mx, __shfl_xor(mx, 4));
                    mx = fmaxf(mx, __shfl_xor(mx, 8));
                    float newm = fmaxf(mrow[mt][r], mx);
                    float alpha = __expf(mrow[mt][r] - newm);
                    mrow[mt][r] = newm;
                    float rs = 0.f;
#pragma unroll
                    for (int nt = 0; nt < 4; ++nt) {
                        float p = __expf(sc[mt][nt][r] - newm);
                        sc[mt][nt][r] = p;
                        rs += p;
                    }
                    rs += __shfl_xor(rs, 1); rs += __shfl_xor(rs, 2);
                    rs += __shfl_xor(rs, 4); rs += __shfl_xor(rs, 8);
                    lrow[mt][r] = lrow[mt][r] * alpha + rs;
#pragma unroll
                    for (int nt = 0; nt < 8; ++nt) o[mt][nt][r] *= alpha;
                }

            // P -> sP (wave-private rows w*32..w*32+31 of 256)
#pragma unroll
            for (int mt = 0; mt < 2; ++mt)
#pragma unroll
                for (int nt = 0; nt < 4; ++nt)
#pragma unroll
                    for (int r = 0; r < 4; ++r) {
                        int rp = w * 32 + mt * 16 + quad * 4 + r;
                        int colh = nt * 16 + col;
                        int c = (colh >> 3) ^ (rp & 7);
                        sP[(size_t)rp * 64 + c * 8 + (colh & 7)] = (_Float16)sc[mt][nt][r];
                    }

            __builtin_amdgcn_s_setprio(1);
#pragma unroll
            for (int kc = 0; kc < 2; ++kc) {
                const int kof = ((kc * 4 + quad) ^ cxor) * 8;
                half8 p0 = *(const half8*)&sP[(size_t)(w * 32 + col) * 64 + kof];
                half8 p1 = *(const half8*)&sP[(size_t)(w * 32 + 16 + col) * 64 + kof];
#pragma unroll
                for (int nt = 0; nt < 8; ++nt) {
                    half8 vf = *(const half8*)&sV[cur][(size_t)(nt * 16 + col) * 64 + kof];
                    o[0][nt] = mfma16(p0, vf, o[0][nt]);
                    o[1][nt] = mfma16(p1, vf, o[1][nt]);
                }
            }
            __builtin_amdgcn_s_setprio(0);
        }

        // single barrier: drains next-tile stage (vmcnt) + guards K/V reuse
        __syncthreads();
    }

#pragma unroll
    for (int mt = 0; mt < 2; ++mt)
#pragma unroll
        for (int r = 0; r < 4; ++r) {
            int rowa = rowbase + mt * 16 + quad * 4 + r;
            float inv = 1.0f / lrow[mt][r];
            _Float16* dst = ctx + ((size_t)b * SEQ + rowa) * HID + h * DHEAD;
#pragma unroll
            for (int nt = 0; nt < 8; ++nt)
                dst[nt * 16 + col] = (_Float16)(o[mt][nt][r] * inv);
        }
}

extern "C" void kernel_launch(void* const* d_in, const int* in_sizes, int n_in,
                              void* d_out, int out_size, void* d_ws, size_t ws_size,
                              hipStream_t stream) {
    const float* hidden = (const float*)d_in[0];
    const int*   tt     = (const int*)d_in[1];
    const int*   pos    = (const int*)d_in[2];
    const float* wvq    = (const float*)d_in[3];
    const float* wlq    = (const float*)d_in[4];
    const float* wvd    = (const float*)d_in[5];
    const float* wld    = (const float*)d_in[6];
    float* out = (float*)d_out;

    char* ws = (char*)d_ws;
    size_t off = 0;
    auto alloc = [&](size_t bytes) {
        char* p = ws + off;
        off += (bytes + 255) & ~(size_t)255;
        return p;
    };
    const size_t TOKB = (size_t)T_TOKENS * HID * sizeof(_Float16);  // 33.5 MB
    _Float16* h16  = (_Float16*)alloc(TOKB);                        // later reused as vT
    _Float16* wvqT = (_Float16*)alloc((size_t)NQKV * HID * 2);
    _Float16* wlqT = (_Float16*)alloc((size_t)NQKV * HID * 2);
    _Float16* wvdT = (_Float16*)alloc((size_t)HID * HID * 2);
    _Float16* wldT = (_Float16*)alloc((size_t)HID * HID * 2);
    _Float16* qb   = (_Float16*)alloc(TOKB);
    _Float16* kb   = (_Float16*)alloc(TOKB);
    _Float16* vtmp = (_Float16*)alloc(TOKB);                        // later reused as ctx
    int* counts = (int*)alloc(2 * sizeof(int));
    int* idx    = (int*)alloc(2 * T_TOKENS * sizeof(int));
    float2* rope = (float2*)alloc((size_t)T_TOKENS * 64 * sizeof(float2));
    _Float16* vT  = h16;    // hidden16 dead after QKV GEMM
    _Float16* ctx = vtmp;   // v token-major dead after transpose_v

    hipMemsetAsync(counts, 0, 2 * sizeof(int), stream);
    route_kernel<<<T_TOKENS / 256, 256, 0, stream>>>(tt, counts, idx);
    rope_table_kernel<<<(T_TOKENS * 64) / 256, 256, 0, stream>>>(pos, rope);
    cvt_f32_f16<<<(T_TOKENS * HID / 4) / 256, 256, 0, stream>>>(hidden, h16, T_TOKENS * HID / 4);
    transpose_cvt<<<dim3(NQKV / 64, HID / 64), 256, 0, stream>>>(wvq, wvqT, HID, NQKV);
    transpose_cvt<<<dim3(NQKV / 64, HID / 64), 256, 0, stream>>>(wlq, wlqT, HID, NQKV);
    transpose_cvt<<<dim3(HID / 64, HID / 64), 256, 0, stream>>>(wvd, wvdT, HID, HID);
    transpose_cvt<<<dim3(HID / 64, HID / 64), 256, 0, stream>>>(wld, wldT, HID, HID);
    gemm_expert256<0, NQKV / 256><<<dim3(NQKV / 256, T_TOKENS / 256, 2), 512, 0, stream>>>(
        h16, wvqT, wlqT, counts, idx, rope, qb, kb, vtmp, nullptr);
    transpose_v<<<dim3(SEQ / 64, DHEAD / 64, NB * NHEADS), 256, 0, stream>>>(vtmp, vT);
    attn_kernel<<<dim3(8 * NB * NHEADS), 512, 0, stream>>>(qb, kb, vT, ctx);
    gemm_expert128<1, HID / 128><<<dim3(HID / 128, T_TOKENS / 128, 2), 256, 0, stream>>>(
        ctx, wvdT, wldT, counts, idx, nullptr, nullptr, nullptr, nullptr, out);
}

// Round 13
// 1497.968 us; speedup vs baseline: 1.0248x; 1.0010x over previous
//
#include <hip/hip_runtime.h>
#include <math.h>

#define SEQ     2048
#define NB      2
#define NHEADS  32
#define DHEAD   128
#define HID     4096
#define NQKV    12288
#define T_TOKENS (NB*SEQ)

typedef _Float16 half8 __attribute__((ext_vector_type(8)));
typedef float v4f __attribute__((ext_vector_type(4)));

__device__ __forceinline__ void gload_lds16(const void* g, void* l) {
    __builtin_amdgcn_global_load_lds(
        (__attribute__((address_space(1))) void*)(void*)(g),
        (__attribute__((address_space(3))) void*)(unsigned)(unsigned long long)(l),
        16, 0, 0);
}

__device__ __forceinline__ v4f mfma16(half8 a, half8 b, v4f c) {
    return __builtin_amdgcn_mfma_f32_16x16x32_f16(a, b, c, 0, 0, 0);
}

// ---------------- routing ----------------
__global__ void route_kernel(const int* __restrict__ tt, int* counts, int* idx) {
    int t = blockIdx.x * blockDim.x + threadIdx.x;
    if (t >= T_TOKENS) return;
    int s = t & (SEQ - 1);
    bool vm = (s < SEQ - 1) && (tt[t] == 1) && (tt[t + 1] == 1);
    int e = vm ? 0 : 1;
    int p = atomicAdd(&counts[e], 1);
    idx[e * T_TOKENS + p] = t;
}

// ---------------- RoPE cos/sin table (accurate, once per call) ----------------
__global__ void rope_table_kernel(const int* __restrict__ pos_ids, float2* __restrict__ tab) {
    int i = blockIdx.x * blockDim.x + threadIdx.x;
    if (i >= T_TOKENS * 64) return;
    int tok = i >> 6, j = i & 63;
    float invf = (float)pow(10000.0, -(double)j * (1.0 / 64.0));
    float ang = (float)pos_ids[tok] * invf;
    double ds, dc;
    sincos((double)ang, &ds, &dc);
    tab[i] = make_float2((float)dc, (float)ds);
}

// ---------------- fp32 -> fp16 ----------------
__global__ void cvt_f32_f16(const float* __restrict__ src, _Float16* __restrict__ dst, int n4) {
    int i = blockIdx.x * blockDim.x + threadIdx.x;
    if (i >= n4) return;
    float4 v = ((const float4*)src)[i];
    union { _Float16 h[4]; uint2 u; } p;
    p.h[0] = (_Float16)v.x; p.h[1] = (_Float16)v.y;
    p.h[2] = (_Float16)v.z; p.h[3] = (_Float16)v.w;
    ((uint2*)dst)[i] = p.u;
}

// ---------------- W [K][N] f32 -> WT [N][K] f16 ----------------
// LDS pad 72 -> 65: write pattern t[cr*4+j][r] has lane stride 65 words ->
// banks (4cr+rr+const)%32 cover each bank exactly 2x per wave = conflict-free
// (was 8-way with stride 72). Reads likewise 2-way. Bit-exact.
__global__ void transpose_cvt(const float* __restrict__ W, _Float16* __restrict__ WT,
                              int K, int N) {
    __shared__ _Float16 t[64][65];
    const int n0 = blockIdx.x * 64, k0 = blockIdx.y * 64;
    const int cr = threadIdx.x & 15, rr = threadIdx.x >> 4;
#pragma unroll
    for (int it = 0; it < 4; ++it) {
        int r = rr + it * 16;
        float4 v = *(const float4*)&W[(size_t)(k0 + r) * N + n0 + cr * 4];
        t[cr*4+0][r] = (_Float16)v.x; t[cr*4+1][r] = (_Float16)v.y;
        t[cr*4+2][r] = (_Float16)v.z; t[cr*4+3][r] = (_Float16)v.w;
    }
    __syncthreads();
#pragma unroll
    for (int it = 0; it < 4; ++it) {
        int r = rr + it * 16;
        union { _Float16 h[4]; uint2 u; } p;
#pragma unroll
        for (int j = 0; j < 4; ++j) p.h[j] = t[r][cr*4+j];
        *(uint2*)&WT[(size_t)(n0 + r) * K + k0 + cr * 4] = p.u;
    }
}

// ---------------- V [b,s,h,d] -> VT [bh][d][s] ----------------
// Same LDS pad 72 -> 65 (same conflict analysis).
__global__ void transpose_v(const _Float16* __restrict__ vin, _Float16* __restrict__ vout) {
    __shared__ _Float16 t[64][65];
    const int s0 = blockIdx.x * 64;
    const int d0 = blockIdx.y * 64;
    const int bh = blockIdx.z;
    const int b = bh >> 5, h = bh & 31;
    const int cr = threadIdx.x & 15, rr = threadIdx.x >> 4;
#pragma unroll
    for (int it = 0; it < 4; ++it) {
        int sl = rr + it * 16;
        union { _Float16 h4[4]; uint2 u; } p;
        p.u = *(const uint2*)&vin[(size_t)(b * SEQ + s0 + sl) * HID + h * DHEAD + d0 + cr * 4];
#pragma unroll
        for (int j = 0; j < 4; ++j) t[cr*4+j][sl] = p.h4[j];
    }
    __syncthreads();
#pragma unroll
    for (int it = 0; it < 4; ++it) {
        int dl = rr + it * 16;
        union { _Float16 h4[4]; uint2 u; } p;
#pragma unroll
        for (int j = 0; j < 4; ++j) p.h4[j] = t[dl][cr*4+j];
        *(uint2*)&vout[((size_t)bh * DHEAD + d0 + dl) * SEQ + s0 + cr * 4] = p.u;
    }
}

// ---------------- gathered-row expert GEMM, 256x256 tile (MODE 0) ----------------
// Round-11/12 measured version, verbatim: 512 threads, 8 waves 2x4, BK=32,
// depth-3 counted-vmcnt(8) pipeline, 4 LDS buffers (128 KB), intra-row chunk
// swizzle. FETCH halved vs 128-tile; MfmaUtil 36.5.
template <int MODE, int NCT>
__global__ __launch_bounds__(512, 2)
void gemm_expert256(const _Float16* __restrict__ A,
                    const _Float16* __restrict__ BT0,
                    const _Float16* __restrict__ BT1,
                    const int* __restrict__ counts,
                    const int* __restrict__ idx_all,
                    const float2* __restrict__ rope,
                    _Float16* __restrict__ qbuf,
                    _Float16* __restrict__ kbuf,
                    _Float16* __restrict__ vbuf,
                    float* __restrict__ out) {
    const int e = blockIdx.z;
    const int count = counts[e];

    const int f   = blockIdx.x + NCT * blockIdx.y;
    const int xcd = f & 7;
    const int g   = f >> 3;
    const int c   = g >> 5;
    const int wi  = g & 31;
    const int rt  = wi >> 1;
    const int ct  = xcd * (NCT / 8) + c * 2 + (wi & 1);

    if (rt * 256 >= count) return;
    const int* idx = idx_all + e * T_TOKENS;
    const _Float16* BT = e ? BT1 : BT0;

    __shared__ _Float16 sA[4][256 * 32];
    __shared__ _Float16 sB[4][256 * 32];

    const int tid = threadIdx.x;
    const int w = tid >> 6, lane = tid & 63;
    const int col = lane & 15, quad = lane >> 4;
    const int wm = w >> 2, wn = w & 3;

    const int schk = (lane & 3) ^ ((lane >> 3) & 3);
    const _Float16* ag[2];
    const _Float16* bg[2];
    int so[2];
#pragma unroll
    for (int o = 0; o < 2; ++o) {
        int r = w * 32 + o * 16 + (lane >> 2);
        int gg = rt * 256 + r; if (gg > count - 1) gg = count - 1;
        ag[o] = A + (size_t)idx[gg] * HID + schk * 8;
        bg[o] = BT + (size_t)(ct * 256 + r) * HID + schk * 8;
        so[o] = (w * 32 + o * 16) * 32;
    }

    v4f acc[8][4];
#pragma unroll
    for (int i = 0; i < 8; ++i)
#pragma unroll
        for (int j = 0; j < 4; ++j) { v4f z = {0.f, 0.f, 0.f, 0.f}; acc[i][j] = z; }

    const int kofq = (quad ^ ((col >> 1) & 3)) * 8;

    auto stage = [&](int buf) {
#pragma unroll
        for (int o = 0; o < 2; ++o) {
            gload_lds16(ag[o], &sA[buf][so[o]]);
            gload_lds16(bg[o], &sB[buf][so[o]]);
            ag[o] += 32; bg[o] += 32;
        }
    };
    auto compute = [&](int cur) {
        half8 a[8], b[4];
#pragma unroll
        for (int i = 0; i < 8; ++i)
            a[i] = *(const half8*)&sA[cur][(wm * 128 + i * 16 + col) * 32 + kofq];
#pragma unroll
        for (int j = 0; j < 4; ++j)
            b[j] = *(const half8*)&sB[cur][((4 * j + wn) * 16 + col) * 32 + kofq];
#pragma unroll
        for (int i = 0; i < 8; ++i)
#pragma unroll
            for (int j = 0; j < 4; ++j)
                acc[i][j] = mfma16(a[i], b[j], acc[i][j]);
    };

    const int NK = HID / 32;
    stage(0); stage(1); stage(2);

    for (int kt = 0; kt < NK - 3; ++kt) {
        asm volatile("s_waitcnt vmcnt(8)" ::: "memory");
        __builtin_amdgcn_s_barrier();
        asm volatile("" ::: "memory");
        stage((kt + 3) & 3);
        compute(kt & 3);
    }
    asm volatile("s_waitcnt vmcnt(8)" ::: "memory");
    __builtin_amdgcn_s_barrier();
    asm volatile("" ::: "memory");
    compute((NK - 3) & 3);
    asm volatile("s_waitcnt vmcnt(4)" ::: "memory");
    __builtin_amdgcn_s_barrier();
    asm volatile("" ::: "memory");
    compute((NK - 2) & 3);
    asm volatile("s_waitcnt vmcnt(0)" ::: "memory");
    __builtin_amdgcn_s_barrier();
    asm volatile("" ::: "memory");
    compute((NK - 1) & 3);

    const int n0 = ct * 256;
    if (MODE == 1) {
#pragma unroll
        for (int i = 0; i < 8; ++i)
#pragma unroll
            for (int r = 0; r < 4; ++r) {
                int rg = rt * 256 + wm * 128 + i * 16 + quad * 4 + r;
                if (rg >= count) continue;
                int tok = idx[rg];
                float* dst = out + (size_t)tok * HID + n0;
#pragma unroll
                for (int j = 0; j < 4; ++j) dst[(4 * j + wn) * 16 + col] = acc[i][j][r];
            }
    } else {
        const int sec = n0 >> 12;
        const int h0 = (n0 >> 7) & 31;
#pragma unroll
        for (int i = 0; i < 8; ++i)
#pragma unroll
            for (int r = 0; r < 4; ++r) {
                int rg = rt * 256 + wm * 128 + i * 16 + quad * 4 + r;
                if (rg >= count) continue;
                int tok = idx[rg];
                int b = tok >> 11, s = tok & (SEQ - 1);
                if (sec == 2) {
#pragma unroll
                    for (int j = 0; j < 4; ++j) {
                        int h = (h0 + (j >> 1)) & 31;
                        vbuf[(size_t)tok * HID + h * DHEAD + (j & 1) * 64 + wn * 16 + col] =
                            (_Float16)acc[i][j][r];
                    }
                } else {
                    const float2* tp = rope + (size_t)tok * 64;
                    int d = wn * 16 + col;
                    float2 cs = tp[d];
#pragma unroll
                    for (int jj = 0; jj < 4; jj += 2) {
                        int h = (h0 + (jj >> 1)) & 31;
                        _Float16* dst = (sec ? kbuf : qbuf) +
                            ((size_t)(b * NHEADS + h) * SEQ + s) * DHEAD;
                        float x = acc[i][jj][r], y = acc[i][jj + 1][r];
                        dst[d]      = (_Float16)(x * cs.x - y * cs.y);
                        dst[d + 64] = (_Float16)(y * cs.x + x * cs.y);
                    }
                }
            }
    }
}

// ---------------- gathered-row expert GEMM, 128x128 tile (MODE 1) ----------------
// Round-6/9 measured version, verbatim: BK=32, 4 waves stacked in M, depth-3
// counted-vmcnt(8) pipeline, 4 LDS buffers, intra-row chunk swizzle.
template <int MODE, int NCT>
__global__ __launch_bounds__(256, 2)
void gemm_expert128(const _Float16* __restrict__ A,
                    const _Float16* __restrict__ BT0,
                    const _Float16* __restrict__ BT1,
                    const int* __restrict__ counts,
                    const int* __restrict__ idx_all,
                    const float2* __restrict__ rope,
                    _Float16* __restrict__ qbuf,
                    _Float16* __restrict__ kbuf,
                    _Float16* __restrict__ vbuf,
                    float* __restrict__ out) {
    const int e = blockIdx.z;
    const int count = counts[e];

    const int f   = blockIdx.x + NCT * blockIdx.y;
    const int xcd = f & 7;
    const int g   = f >> 3;
    const int c   = g >> 6;
    const int wi  = g & 63;
    const int rt  = wi >> 1;
    const int ct  = xcd * (NCT / 8) + c * 2 + (wi & 1);

    if (rt * 128 >= count) return;
    const int* idx = idx_all + e * T_TOKENS;
    const _Float16* BT = e ? BT1 : BT0;

    __shared__ _Float16 sA[4][128 * 32];
    __shared__ _Float16 sB[4][128 * 32];

    const int tid = threadIdx.x;
    const int w = tid >> 6, lane = tid & 63;
    const int col = lane & 15, quad = lane >> 4;

    const int r0 = (w * 2 + 0) * 16 + (lane >> 2);
    const int r1 = (w * 2 + 1) * 16 + (lane >> 2);
    int g0 = rt * 128 + r0; if (g0 > count - 1) g0 = count - 1;
    int g1 = rt * 128 + r1; if (g1 > count - 1) g1 = count - 1;
    const int tok0 = idx[g0], tok1 = idx[g1];
    const int schk = (lane & 3) ^ ((lane >> 3) & 3);
    const _Float16* ag0 = A + (size_t)tok0 * HID + schk * 8;
    const _Float16* ag1 = A + (size_t)tok1 * HID + schk * 8;
    const _Float16* bg0 = BT + (size_t)(ct * 128 + r0) * HID + schk * 8;
    const _Float16* bg1 = BT + (size_t)(ct * 128 + r1) * HID + schk * 8;
    const int sa_off0 = (w * 2 + 0) * 512;
    const int sa_off1 = (w * 2 + 1) * 512;

    v4f acc[2][8];
#pragma unroll
    for (int i = 0; i < 2; ++i)
#pragma unroll
        for (int j = 0; j < 8; ++j) { v4f z = {0.f, 0.f, 0.f, 0.f}; acc[i][j] = z; }

    const int kofq = (quad ^ ((col >> 1) & 3)) * 8;
    const int am0 = (w * 32 + col) * 32 + kofq;
    const int am1 = am0 + 16 * 32;

    auto stage = [&](int buf) {
        gload_lds16(ag0, &sA[buf][sa_off0]); gload_lds16(ag1, &sA[buf][sa_off1]);
        gload_lds16(bg0, &sB[buf][sa_off0]); gload_lds16(bg1, &sB[buf][sa_off1]);
        ag0 += 32; ag1 += 32; bg0 += 32; bg1 += 32;
    };
    auto compute = [&](int cur) {
        half8 a0 = *(const half8*)&sA[cur][am0];
        half8 a1 = *(const half8*)&sA[cur][am1];
#pragma unroll
        for (int nt = 0; nt < 8; ++nt) {
            half8 b = *(const half8*)&sB[cur][(nt * 16 + col) * 32 + kofq];
            acc[0][nt] = mfma16(a0, b, acc[0][nt]);
            acc[1][nt] = mfma16(a1, b, acc[1][nt]);
        }
    };

    const int NK = HID / 32;
    stage(0); stage(1); stage(2);

    for (int kt = 0; kt < NK - 3; ++kt) {
        asm volatile("s_waitcnt vmcnt(8)" ::: "memory");
        __builtin_amdgcn_s_barrier();
        asm volatile("" ::: "memory");
        stage((kt + 3) & 3);
        compute(kt & 3);
    }
    asm volatile("s_waitcnt vmcnt(8)" ::: "memory");
    __builtin_amdgcn_s_barrier();
    asm volatile("" ::: "memory");
    compute((NK - 3) & 3);
    asm volatile("s_waitcnt vmcnt(4)" ::: "memory");
    __builtin_amdgcn_s_barrier();
    asm volatile("" ::: "memory");
    compute((NK - 2) & 3);
    asm volatile("s_waitcnt vmcnt(0)" ::: "memory");
    __builtin_amdgcn_s_barrier();
    asm volatile("" ::: "memory");
    compute((NK - 1) & 3);

    const int n0 = ct * 128;
    if (MODE == 1) {
#pragma unroll
        for (int mt = 0; mt < 2; ++mt)
#pragma unroll
            for (int r = 0; r < 4; ++r) {
                int rg = rt * 128 + w * 32 + mt * 16 + quad * 4 + r;
                if (rg >= count) continue;
                int tok = idx[rg];
                float* dst = out + (size_t)tok * HID + n0;
#pragma unroll
                for (int nt = 0; nt < 8; ++nt) dst[nt * 16 + col] = acc[mt][nt][r];
            }
    } else {
        const int sec = n0 >> 12;
        const int h = (n0 >> 7) & 31;
#pragma unroll
        for (int mt = 0; mt < 2; ++mt)
#pragma unroll
            for (int r = 0; r < 4; ++r) {
                int rg = rt * 128 + w * 32 + mt * 16 + quad * 4 + r;
                if (rg >= count) continue;
                int tok = idx[rg];
                int b = tok >> 11, s = tok & (SEQ - 1);
                if (sec == 2) {
                    _Float16* dst = vbuf + (size_t)tok * HID + h * DHEAD;
#pragma unroll
                    for (int nt = 0; nt < 8; ++nt) dst[nt * 16 + col] = (_Float16)acc[mt][nt][r];
                } else {
                    _Float16* dst = (sec ? kbuf : qbuf) + ((size_t)(b * NHEADS + h) * SEQ + s) * DHEAD;
                    const float2* tp = rope + (size_t)tok * 64;
#pragma unroll
                    for (int nt = 0; nt < 4; ++nt) {
                        int d = nt * 16 + col;
                        float2 cs = tp[d];
                        float x = acc[mt][nt][r], y = acc[mt][nt + 4][r];
                        dst[d]      = (_Float16)(x * cs.x - y * cs.y);
                        dst[d + 64] = (_Float16)(y * cs.x + x * cs.y);
                    }
                }
            }
    }
}

// ---------------- flash attention (v5: 8-wave QBLK=256, round-12 best) ------
// One block = 256 q-rows (8 waves x 32 rows), 512 threads, 1 block/CU
// (LDS 96KB). K/V staged ONCE per kv-tile for 256 q-rows (fetch+staging per
// CU halved vs 128-row blocks). Same prefetch loop, same swizzles, single
// barrier per tile, per-wave early-skip of fully-masked tiles.
__global__ __launch_bounds__(512, 1)
void attn_kernel(const _Float16* __restrict__ qbuf,
                 const _Float16* __restrict__ kbuf,
                 const _Float16* __restrict__ vt,
                 _Float16* __restrict__ ctx) {
    const int f   = blockIdx.x;            // 0..511
    const int xcd = f & 7;
    const int t   = f >> 3;                // 0..63
    const int rr  = t >> 5;                // generation 0..1
    const int s   = t & 31;
    const int u   = s & 3;
    const int bh  = xcd * 8 + (s >> 2);
    const int qt  = rr ? (7 - u) : u;      // 0..7 (256-row q tiles)

    const int b = bh >> 5, h = bh & 31;
    const int tid = threadIdx.x;
    const int w = tid >> 6, lane = tid & 63;   // w 0..7
    const int col = lane & 15, quad = lane >> 4;

    __shared__ _Float16 sK[2][64 * 128];   // K [64][128], swizzled, double-buffered
    __shared__ _Float16 sV[2][128 * 64];   // V [d=128][s=64], swizzled, double-buffered
    __shared__ _Float16 sP[256 * 64];      // P [256][64], swizzled, per-wave rows

    half8 qf[2][4];
    const _Float16 qscale = (_Float16)0.08838834764831845f;  // 1/sqrt(128)
#pragma unroll
    for (int mt = 0; mt < 2; ++mt)
#pragma unroll
        for (int kc = 0; kc < 4; ++kc) {
            int row = qt * 256 + w * 32 + mt * 16 + col;
            half8 v = *(const half8*)&qbuf[((size_t)bh * SEQ + row) * DHEAD + kc * 32 + quad * 8];
            qf[mt][kc] = v * qscale;
        }

    float mrow[2][4], lrow[2][4];
    v4f o[2][8];
#pragma unroll
    for (int mt = 0; mt < 2; ++mt)
#pragma unroll
        for (int r = 0; r < 4; ++r) { mrow[mt][r] = -3.0e38f; lrow[mt][r] = 0.f; }
#pragma unroll
    for (int i = 0; i < 2; ++i)
#pragma unroll
        for (int j = 0; j < 8; ++j) { v4f z = {0.f, 0.f, 0.f, 0.f}; o[i][j] = z; }

    const int cxor = col & 7;
    const int vs_chk = (lane & 7) ^ (lane >> 3);
    const int nkt = 4 * qt + 4;
    const int rowbase = qt * 256 + w * 32;     // this wave's first q-row

    const _Float16* kg0 = kbuf + (size_t)bh * SEQ * DHEAD;
    const _Float16* vg0 = vt + (size_t)bh * DHEAD * SEQ;

    auto stage = [&](int kt, int buf) {
        const _Float16* kg = kg0 + (size_t)kt * 64 * DHEAD;
        const _Float16* vg = vg0 + kt * 64;
#pragma unroll
        for (int op = 0; op < 2; ++op) {
            int r0 = (w * 2 + op) * 4;
            int krow = r0 + quad;
            int kcs = col ^ (krow & 7);
            gload_lds16(kg + (size_t)krow * DHEAD + kcs * 8, &sK[buf][r0 * 128]);
            int d0 = (w * 2 + op) * 8;
            int vrow = d0 + (lane >> 3);
            gload_lds16(vg + (size_t)vrow * SEQ + vs_chk * 8, &sV[buf][d0 * 64]);
        }
    };

    stage(0, 0);
    __syncthreads();   // drain prologue stage

    for (int kt = 0; kt < nkt; ++kt) {
        const int cur = kt & 1;
        if (kt + 1 < nkt) stage(kt + 1, cur ^ 1);   // prefetch under compute

        if (kt * 64 <= rowbase + 31) {
            v4f sc[2][4];
#pragma unroll
            for (int i = 0; i < 2; ++i)
#pragma unroll
                for (int j = 0; j < 4; ++j) { v4f z = {0.f, 0.f, 0.f, 0.f}; sc[i][j] = z; }
            __builtin_amdgcn_s_setprio(1);
#pragma unroll
            for (int kc = 0; kc < 4; ++kc) {
                const int kof = ((kc * 4 + quad) ^ cxor) * 8;
#pragma unroll
                for (int nt = 0; nt < 4; ++nt) {
                    half8 bf = *(const half8*)&sK[cur][(size_t)(nt * 16 + col) * 128 + kof];
                    sc[0][nt] = mfma16(qf[0][kc], bf, sc[0][nt]);
                    sc[1][nt] = mfma16(qf[1][kc], bf, sc[1][nt]);
                }
            }
            __builtin_amdgcn_s_setprio(0);

            if (kt * 64 + 63 > rowbase) {   // tile touches this wave's diagonal
#pragma unroll
                for (int mt = 0; mt < 2; ++mt)
#pragma unroll
                    for (int nt = 0; nt < 4; ++nt)
#pragma unroll
                        for (int r = 0; r < 4; ++r) {
                            int rowa = rowbase + mt * 16 + quad * 4 + r;
                            int cola = kt * 64 + nt * 16 + col;
                            if (cola > rowa) sc[mt][nt][r] = -3.0e38f;
                        }
            }

#pragma unroll
            for (int mt = 0; mt < 2; ++mt)
#pragma unroll
                for (int r = 0; r < 4; ++r) {
                    float mx = sc[mt][0][r];
#pragma unroll
                    for (int nt = 1; nt < 4; ++nt) mx = fmaxf(mx, sc[mt][nt][r]);
                    mx = fmaxf(mx, __shfl_xor(mx, 1));
                    mx = fmaxf(mx, __shfl_xor(mx, 2));
                    mx = fmaxf(mx, __shfl_xor(mx, 4));
                    mx = fmaxf(mx, __shfl_xor(mx, 8));
                    float newm = fmaxf(mrow[mt][r], mx);
                    float alpha = __expf(mrow[mt][r] - newm);
                    mrow[mt][r] = newm;
                    float rs = 0.f;
#pragma unroll
                    for (int nt = 0; nt < 4; ++nt) {
                        float p = __expf(sc[mt][nt][r] - newm);
                        sc[mt][nt][r] = p;
                        rs += p;
                    }
                    rs += __shfl_xor(rs, 1); rs += __shfl_xor(rs, 2);
                    rs += __shfl_xor(rs, 4); rs += __shfl_xor(rs, 8);
                    lrow[mt][r] = lrow[mt][r] * alpha + rs;
#pragma unroll
                    for (int nt = 0; nt < 8; ++nt) o[mt][nt][r] *= alpha;
                }

            // P -> sP (wave-private rows w*32..w*32+31 of 256)
#pragma unroll
            for (int mt = 0; mt < 2; ++mt)
#pragma unroll
                for (int nt = 0; nt < 4; ++nt)
#pragma unroll
                    for (int r = 0; r < 4; ++r) {
                        int rp = w * 32 + mt * 16 + quad * 4 + r;
                        int colh = nt * 16 + col;
                        int c = (colh >> 3) ^ (rp & 7);
                        sP[(size_t)rp * 64 + c * 8 + (colh & 7)] = (_Float16)sc[mt][nt][r];
                    }

            __builtin_amdgcn_s_setprio(1);
#pragma unroll
            for (int kc = 0; kc < 2; ++kc) {
                const int kof = ((kc * 4 + quad) ^ cxor) * 8;
                half8 p0 = *(const half8*)&sP[(size_t)(w * 32 + col) * 64 + kof];
                half8 p1 = *(const half8*)&sP[(size_t)(w * 32 + 16 + col) * 64 + kof];
#pragma unroll
                for (int nt = 0; nt < 8; ++nt) {
                    half8 vf = *(const half8*)&sV[cur][(size_t)(nt * 16 + col) * 64 + kof];
                    o[0][nt] = mfma16(p0, vf, o[0][nt]);
                    o[1][nt] = mfma16(p1, vf, o[1][nt]);
                }
            }
            __builtin_amdgcn_s_setprio(0);
        }

        // single barrier: drains next-tile stage (vmcnt) + guards K/V reuse
        __syncthreads();
    }

#pragma unroll
    for (int mt = 0; mt < 2; ++mt)
#pragma unroll
        for (int r = 0; r < 4; ++r) {
            int rowa = rowbase + mt * 16 + quad * 4 + r;
            float inv = 1.0f / lrow[mt][r];
            _Float16* dst = ctx + ((size_t)b * SEQ + rowa) * HID + h * DHEAD;
#pragma unroll
            for (int nt = 0; nt < 8; ++nt)
                dst[nt * 16 + col] = (_Float16)(o[mt][nt][r] * inv);
        }
}

extern "C" void kernel_launch(void* const* d_in, const int* in_sizes, int n_in,
                              void* d_out, int out_size, void* d_ws, size_t ws_size,
                              hipStream_t stream) {
    const float* hidden = (const float*)d_in[0];
    const int*   tt     = (const int*)d_in[1];
    const int*   pos    = (const int*)d_in[2];
    const float* wvq    = (const float*)d_in[3];
    const float* wlq    = (const float*)d_in[4];
    const float* wvd    = (const float*)d_in[5];
    const float* wld    = (const float*)d_in[6];
    float* out = (float*)d_out;

    char* ws = (char*)d_ws;
    size_t off = 0;
    auto alloc = [&](size_t bytes) {
        char* p = ws + off;
        off += (bytes + 255) & ~(size_t)255;
        return p;
    };
    const size_t TOKB = (size_t)T_TOKENS * HID * sizeof(_Float16);  // 33.5 MB
    _Float16* h16  = (_Float16*)alloc(TOKB);                        // later reused as vT
    _Float16* wvqT = (_Float16*)alloc((size_t)NQKV * HID * 2);
    _Float16* wlqT = (_Float16*)alloc((size_t)NQKV * HID * 2);
    _Float16* wvdT = (_Float16*)alloc((size_t)HID * HID * 2);
    _Float16* wldT = (_Float16*)alloc((size_t)HID * HID * 2);
    _Float16* qb   = (_Float16*)alloc(TOKB);
    _Float16* kb   = (_Float16*)alloc(TOKB);
    _Float16* vtmp = (_Float16*)alloc(TOKB);                        // later reused as ctx
    int* counts = (int*)alloc(2 * sizeof(int));
    int* idx    = (int*)alloc(2 * T_TOKENS * sizeof(int));
    float2* rope = (float2*)alloc((size_t)T_TOKENS * 64 * sizeof(float2));
    _Float16* vT  = h16;    // hidden16 dead after QKV GEMM
    _Float16* ctx = vtmp;   // v token-major dead after transpose_v

    hipMemsetAsync(counts, 0, 2 * sizeof(int), stream);
    route_kernel<<<T_TOKENS / 256, 256, 0, stream>>>(tt, counts, idx);
    rope_table_kernel<<<(T_TOKENS * 64) / 256, 256, 0, stream>>>(pos, rope);
    cvt_f32_f16<<<(T_TOKENS * HID / 4) / 256, 256, 0, stream>>>(hidden, h16, T_TOKENS * HID / 4);
    transpose_cvt<<<dim3(NQKV / 64, HID / 64), 256, 0, stream>>>(wvq, wvqT, HID, NQKV);
    transpose_cvt<<<dim3(NQKV / 64, HID / 64), 256, 0, stream>>>(wlq, wlqT, HID, NQKV);
    transpose_cvt<<<dim3(HID / 64, HID / 64), 256, 0, stream>>>(wvd, wvdT, HID, HID);
    transpose_cvt<<<dim3(HID / 64, HID / 64), 256, 0, stream>>>(wld, wldT, HID, HID);
    gemm_expert256<0, NQKV / 256><<<dim3(NQKV / 256, T_TOKENS / 256, 2), 512, 0, stream>>>(
        h16, wvqT, wlqT, counts, idx, rope, qb, kb, vtmp, nullptr);
    transpose_v<<<dim3(SEQ / 64, DHEAD / 64, NB * NHEADS), 256, 0, stream>>>(vtmp, vT);
    attn_kernel<<<dim3(8 * NB * NHEADS), 512, 0, stream>>>(qb, kb, vT, ctx);
    gemm_expert128<1, HID / 128><<<dim3(HID / 128, T_TOKENS / 128, 2), 256, 0, stream>>>(
        ctx, wvdT, wldT, counts, idx, nullptr, nullptr, nullptr, nullptr, out);
}